// Round 1
// baseline (519.655 us; speedup 1.0000x reference)
//
#include <hip/hip_runtime.h>

// Problem constants: B=2, T=2048, C=1024, H=16, HS=64
typedef unsigned short u16;
typedef unsigned int u32;
typedef __bf16 bf16x8 __attribute__((ext_vector_type(8)));
typedef float f32x4 __attribute__((ext_vector_type(4)));
typedef u16 u16x4 __attribute__((ext_vector_type(4)));

__device__ __forceinline__ u16 f2bf(float f) {
  u32 u = __builtin_bit_cast(u32, f);
  u += 0x7fffu + ((u >> 16) & 1u);   // round-to-nearest-even
  return (u16)(u >> 16);
}

__device__ __forceinline__ void gld16(const void* g, void* l) {
  __builtin_amdgcn_global_load_lds(
      (const __attribute__((address_space(1))) void*)g,
      (__attribute__((address_space(3))) void*)l, 16, 0, 0);
}

// ------------------------- prep kernels -------------------------
__global__ __launch_bounds__(256) void k_conv_x(const float* __restrict__ x,
                                                u16* __restrict__ xb) {
  int i = (blockIdx.x * 256 + threadIdx.x) * 4;
  float4 v = *(const float4*)(x + i);
  u16x4 o = { f2bf(v.x), f2bf(v.y), f2bf(v.z), f2bf(v.w) };
  *(u16x4*)(xb + i) = o;
}

// dst[Cc][R] (bf16) = transpose of src[R][Cc] (f32)
__global__ __launch_bounds__(256) void k_transpose(const float* __restrict__ src,
                                                   u16* __restrict__ dst,
                                                   int R, int Cc) {
  __shared__ float tile[32][33];
  int x = threadIdx.x & 31, y = threadIdx.x >> 5;
  int c0 = blockIdx.x * 32, r0 = blockIdx.y * 32;
  for (int i = 0; i < 4; ++i)
    tile[y + 8 * i][x] = src[(size_t)(r0 + y + 8 * i) * Cc + c0 + x];
  __syncthreads();
  for (int i = 0; i < 4; ++i)
    dst[(size_t)(c0 + y + 8 * i) * R + r0 + x] = f2bf(tile[x][y + 8 * i]);
}

// tab[t*32+d] = (cos, sin) of t * 10000^(-d/32)
__global__ __launch_bounds__(256) void k_rope_tab(float2* __restrict__ tab) {
  int i = blockIdx.x * 256 + threadIdx.x;  // 0..65535
  int t = i >> 5, d = i & 31;
  float theta = expf(-(float)d * 0.28782313662425575f);  // ln(10000)/32
  float ang = (float)t * theta;
  tab[i] = make_float2(cosf(ang), sinf(ang));
}

// --------------- QKV GEMM + bias + RoPE + scatter ---------------
// C[m][n] = Xb[m][:] . Wt[n][:],  m = b*2048+t, n = h*192 + p
// p<64: Q(hs=p)  64<=p<128: K(hs=p-64)  else V(hs=p-128)
__global__ __launch_bounds__(256) void k_qkv(
    const u16* __restrict__ Xb,      // [4096][1024] bf16
    const u16* __restrict__ Wt,      // [3072][1024] bf16 (W_qkv^T)
    const float* __restrict__ bias,  // [3072]
    const float2* __restrict__ rope, // [2048][32]
    u16* __restrict__ Qg,            // [B,H,T,HS]
    u16* __restrict__ Kg,            // [B,H,T,HS]
    u16* __restrict__ Vt) {          // [B,H,HS,T]
  __shared__ alignas(16) u16 As[128 * 32];
  __shared__ alignas(16) u16 Bs[128 * 32];
  const int tid = threadIdx.x;
  const int lane = tid & 63, w = tid >> 6;
  const int quad = lane >> 4, l15 = lane & 15;
  const int m0 = blockIdx.y * 128, n0 = blockIdx.x * 128;
  const int lr = lane >> 2, lc = (lane & 3) * 8;
  const int wm = (w & 1) * 64, wn = (w >> 1) * 64;
  const f32x4 vzero = {0.f, 0.f, 0.f, 0.f};

  f32x4 acc[4][4];
  for (int i = 0; i < 4; ++i)
    for (int j = 0; j < 4; ++j) acc[i][j] = vzero;

  for (int kt = 0; kt < 1024; kt += 32) {
    __syncthreads();
    for (int i = 0; i < 2; ++i) {
      int row = w * 32 + i * 16;
      gld16(Xb + (size_t)(m0 + row + lr) * 1024 + kt + lc, &As[row * 32]);
      gld16(Wt + (size_t)(n0 + row + lr) * 1024 + kt + lc, &Bs[row * 32]);
    }
    __syncthreads();
    bf16x8 a[4], b[4];
    for (int mt = 0; mt < 4; ++mt)
      a[mt] = *(const bf16x8*)&As[(wm + mt * 16 + l15) * 32 + quad * 8];
    for (int nt = 0; nt < 4; ++nt)
      b[nt] = *(const bf16x8*)&Bs[(wn + nt * 16 + l15) * 32 + quad * 8];
    for (int mt = 0; mt < 4; ++mt)
      for (int nt = 0; nt < 4; ++nt)
        acc[mt][nt] = __builtin_amdgcn_mfma_f32_16x16x32_bf16(
            a[mt], b[nt], acc[mt][nt], 0, 0, 0);
  }

  for (int nt = 0; nt < 4; ++nt) {
    int n = n0 + wn + nt * 16 + l15;
    float bv = bias[n];
    int h = n / 192, p = n - h * 192;
    int hs = p & 63;
    for (int mt = 0; mt < 4; ++mt) {
      for (int r = 0; r < 4; ++r) {
        int m = m0 + wm + mt * 16 + quad * 4 + r;
        int bb = m >> 11, t = m & 2047;
        float v = acc[mt][nt][r] + bv;
        // RoPE pair lives in adjacent column = adjacent lane (n parity == lane parity)
        float partner = __shfl_xor(v, 1, 64);
        if (p < 128) {
          float2 cs = rope[t * 32 + (hs >> 1)];
          float outv = (hs & 1) ? fmaf(partner, cs.y, v * cs.x)    // x0*s + x1*c
                                : fmaf(-partner, cs.y, v * cs.x);  // x0*c - x1*s
          size_t idx = ((size_t)(bb * 16 + h) * 2048 + t) * 64 + hs;
          u16 o = f2bf(outv);
          if (p < 64) Qg[idx] = o; else Kg[idx] = o;
        } else {
          Vt[((size_t)(bb * 16 + h) * 64 + hs) * 2048 + t] = f2bf(v);
        }
      }
    }
  }
}

// ------------------- flash attention (causal) -------------------
// grid: (16 q-tiles, 32 bh). BQ=128, BKV=64. 4 waves, each owns 32 q-rows.
__global__ __launch_bounds__(256) void k_attn(
    const u16* __restrict__ Qg, const u16* __restrict__ Kg,
    const u16* __restrict__ Vt, u16* __restrict__ Og) {  // Og: [4096][1024] bf16
  __shared__ alignas(16) u16 Qs[128 * 64];
  __shared__ alignas(16) u16 Ks[64 * 64];
  __shared__ alignas(16) u16 Vs[64 * 64];   // [hs][kk]
  __shared__ alignas(16) u16 Ps[128 * 64];
  const int tid = threadIdx.x, lane = tid & 63, w = tid >> 6;
  const int quad = lane >> 4, l15 = lane & 15;
  const int qt = 15 - blockIdx.x;  // heavy tiles first
  const int bh = blockIdx.y;
  const int q0 = qt * 128;
  const u16* Qh = Qg + (size_t)bh * 2048 * 64;
  const u16* Kh = Kg + (size_t)bh * 2048 * 64;
  const u16* Vh = Vt + (size_t)bh * 64 * 2048;
  const f32x4 vzero = {0.f, 0.f, 0.f, 0.f};
  const float LOG2E = 1.4426950408889634f;

  {  // stage Q tile once: 128x64
    int r8 = lane >> 3, c8 = (lane & 7) * 8;
    for (int i = 0; i < 4; ++i) {
      int row = w * 32 + i * 8;
      gld16(Qh + (size_t)(q0 + row + r8) * 64 + c8, &Qs[row * 64]);
    }
  }

  float mst[2][4], lst[2][4];
  f32x4 O[2][4];
  for (int mt = 0; mt < 2; ++mt)
    for (int r = 0; r < 4; ++r) { mst[mt][r] = -1e30f; lst[mt][r] = 0.f; }
  for (int mt = 0; mt < 2; ++mt)
    for (int nt = 0; nt < 4; ++nt) O[mt][nt] = vzero;

  const int nk = 2 * qt + 2;
  for (int kb = 0; kb < nk; ++kb) {
    int k0 = kb * 64;
    __syncthreads();  // prev tile's MFMAs done; also drains Q staging (vmcnt)
    {
      int r8 = lane >> 3, c8 = (lane & 7) * 8;
      for (int i = 0; i < 2; ++i) {
        int row = w * 16 + i * 8;
        gld16(Kh + (size_t)(k0 + row + r8) * 64 + c8, &Ks[row * 64]);
        gld16(Vh + (size_t)(row + r8) * 2048 + k0 + c8, &Vs[row * 64]);
      }
    }
    __syncthreads();

    // S = Q K^T for this wave's 32 rows x 64 cols
    f32x4 s[2][4];
    for (int mt = 0; mt < 2; ++mt)
      for (int nt = 0; nt < 4; ++nt) s[mt][nt] = vzero;
    for (int ks = 0; ks < 2; ++ks) {
      bf16x8 a[2], b[4];
      for (int mt = 0; mt < 2; ++mt)
        a[mt] = *(const bf16x8*)&Qs[(w * 32 + mt * 16 + l15) * 64 + ks * 32 + quad * 8];
      for (int nt = 0; nt < 4; ++nt)
        b[nt] = *(const bf16x8*)&Ks[(nt * 16 + l15) * 64 + ks * 32 + quad * 8];
      for (int mt = 0; mt < 2; ++mt)
        for (int nt = 0; nt < 4; ++nt)
          s[mt][nt] = __builtin_amdgcn_mfma_f32_16x16x32_bf16(a[mt], b[nt], s[mt][nt], 0, 0, 0);
    }

    // scale + causal mask + online softmax
    for (int mt = 0; mt < 2; ++mt) {
      for (int r = 0; r < 4; ++r) {
        int tq = q0 + w * 32 + mt * 16 + quad * 4 + r;
        float rmax = -1e30f;
        for (int nt = 0; nt < 4; ++nt) {
          int tk = k0 + nt * 16 + l15;
          float sv = s[mt][nt][r] * 0.125f;
          sv = (tk <= tq) ? sv : -1e30f;
          s[mt][nt][r] = sv;
          rmax = fmaxf(rmax, sv);
        }
        for (int msk = 1; msk < 16; msk <<= 1)
          rmax = fmaxf(rmax, __shfl_xor(rmax, msk, 64));
        float mold = mst[mt][r];
        float mnew = fmaxf(mold, rmax);
        float alpha = __builtin_amdgcn_exp2f((mold - mnew) * LOG2E);
        mst[mt][r] = mnew;
        float rsum = 0.f;
        for (int nt = 0; nt < 4; ++nt) {
          float pv = __builtin_amdgcn_exp2f((s[mt][nt][r] - mnew) * LOG2E);
          rsum += pv;
          Ps[(w * 32 + mt * 16 + quad * 4 + r) * 64 + nt * 16 + l15] = f2bf(pv);
        }
        for (int msk = 1; msk < 16; msk <<= 1)
          rsum += __shfl_xor(rsum, msk, 64);
        lst[mt][r] = lst[mt][r] * alpha + rsum;
        for (int nt2 = 0; nt2 < 4; ++nt2) O[mt][nt2][r] *= alpha;
      }
    }
    __syncthreads();  // Ps write ordering safety (reads are intra-wave)

    // O += P V  (K-dim = 64)
    for (int ks = 0; ks < 2; ++ks) {
      bf16x8 a[2], b[4];
      for (int mt = 0; mt < 2; ++mt)
        a[mt] = *(const bf16x8*)&Ps[(w * 32 + mt * 16 + l15) * 64 + ks * 32 + quad * 8];
      for (int nt = 0; nt < 4; ++nt)
        b[nt] = *(const bf16x8*)&Vs[(nt * 16 + l15) * 64 + ks * 32 + quad * 8];
      for (int mt = 0; mt < 2; ++mt)
        for (int nt = 0; nt < 4; ++nt)
          O[mt][nt] = __builtin_amdgcn_mfma_f32_16x16x32_bf16(a[mt], b[nt], O[mt][nt], 0, 0, 0);
    }
  }

  // epilogue: normalize, write att out as [b*2048+t][h*64+hs] bf16
  const int bb = bh >> 4, h = bh & 15;
  for (int mt = 0; mt < 2; ++mt)
    for (int nt = 0; nt < 4; ++nt)
      for (int r = 0; r < 4; ++r) {
        int t = q0 + w * 32 + mt * 16 + quad * 4 + r;
        int col = h * 64 + nt * 16 + l15;
        float val = O[mt][nt][r] / lst[mt][r];
        Og[(size_t)(bb * 2048 + t) * 1024 + col] = f2bf(val);
      }
}

// --------------------- output projection GEMM ---------------------
__global__ __launch_bounds__(256) void k_proj(
    const u16* __restrict__ Ag,      // [4096][1024] bf16
    const u16* __restrict__ Wt,      // [1024][1024] bf16 (W_proj^T)
    const float* __restrict__ bias,  // [1024]
    float* __restrict__ out) {       // [4096][1024] f32
  __shared__ alignas(16) u16 As[128 * 32];
  __shared__ alignas(16) u16 Bs[128 * 32];
  const int tid = threadIdx.x;
  const int lane = tid & 63, w = tid >> 6;
  const int quad = lane >> 4, l15 = lane & 15;
  const int m0 = blockIdx.y * 128, n0 = blockIdx.x * 128;
  const int lr = lane >> 2, lc = (lane & 3) * 8;
  const int wm = (w & 1) * 64, wn = (w >> 1) * 64;
  const f32x4 vzero = {0.f, 0.f, 0.f, 0.f};

  f32x4 acc[4][4];
  for (int i = 0; i < 4; ++i)
    for (int j = 0; j < 4; ++j) acc[i][j] = vzero;

  for (int kt = 0; kt < 1024; kt += 32) {
    __syncthreads();
    for (int i = 0; i < 2; ++i) {
      int row = w * 32 + i * 16;
      gld16(Ag + (size_t)(m0 + row + lr) * 1024 + kt + lc, &As[row * 32]);
      gld16(Wt + (size_t)(n0 + row + lr) * 1024 + kt + lc, &Bs[row * 32]);
    }
    __syncthreads();
    bf16x8 a[4], b[4];
    for (int mt = 0; mt < 4; ++mt)
      a[mt] = *(const bf16x8*)&As[(wm + mt * 16 + l15) * 32 + quad * 8];
    for (int nt = 0; nt < 4; ++nt)
      b[nt] = *(const bf16x8*)&Bs[(wn + nt * 16 + l15) * 32 + quad * 8];
    for (int mt = 0; mt < 4; ++mt)
      for (int nt = 0; nt < 4; ++nt)
        acc[mt][nt] = __builtin_amdgcn_mfma_f32_16x16x32_bf16(
            a[mt], b[nt], acc[mt][nt], 0, 0, 0);
  }

  for (int nt = 0; nt < 4; ++nt) {
    int n = n0 + wn + nt * 16 + l15;
    float bv = bias[n];
    for (int mt = 0; mt < 4; ++mt)
      for (int r = 0; r < 4; ++r) {
        int m = m0 + wm + mt * 16 + quad * 4 + r;
        out[(size_t)m * 1024 + n] = acc[mt][nt][r] + bv;
      }
  }
}

extern "C" void kernel_launch(void* const* d_in, const int* in_sizes, int n_in,
                              void* d_out, int out_size, void* d_ws, size_t ws_size,
                              hipStream_t stream) {
  (void)in_sizes; (void)n_in; (void)out_size; (void)ws_size;
  const float* x     = (const float*)d_in[0];
  const float* Wqkv  = (const float*)d_in[1];
  const float* bqkv  = (const float*)d_in[2];
  const float* Wproj = (const float*)d_in[3];
  const float* bproj = (const float*)d_in[4];
  float* out = (float*)d_out;

  char* ws = (char*)d_ws;
  size_t off = 0;
  u16* Xb    = (u16*)(ws + off); off += (size_t)4096 * 1024 * 2;   // x bf16
  u16* Wqkvt = (u16*)(ws + off); off += (size_t)3072 * 1024 * 2;   // W_qkv^T bf16
  u16* Wpt   = (u16*)(ws + off); off += (size_t)1024 * 1024 * 2;   // W_proj^T bf16
  u16* Qg    = (u16*)(ws + off); off += (size_t)2 * 16 * 2048 * 64 * 2;
  u16* Kg    = (u16*)(ws + off); off += (size_t)2 * 16 * 2048 * 64 * 2;
  u16* Vt    = (u16*)(ws + off); off += (size_t)2 * 16 * 64 * 2048 * 2;
  u16* Att   = (u16*)(ws + off); off += (size_t)4096 * 1024 * 2;
  float2* rope = (float2*)(ws + off); off += (size_t)2048 * 32 * sizeof(float2);

  k_conv_x<<<4096, 256, 0, stream>>>(x, Xb);
  k_transpose<<<dim3(96, 32), 256, 0, stream>>>(Wqkv, Wqkvt, 1024, 3072);
  k_transpose<<<dim3(32, 32), 256, 0, stream>>>(Wproj, Wpt, 1024, 1024);
  k_rope_tab<<<256, 256, 0, stream>>>(rope);
  k_qkv<<<dim3(24, 32), 256, 0, stream>>>(Xb, Wqkvt, bqkv, rope, Qg, Kg, Vt);
  k_attn<<<dim3(16, 32), 256, 0, stream>>>(Qg, Kg, Vt, Att);
  k_proj<<<dim3(8, 32), 256, 0, stream>>>(Att, Wpt, bproj, out);
}

// Round 2
// 309.050 us; speedup vs baseline: 1.6815x; 1.6815x over previous
//
#include <hip/hip_runtime.h>

// Problem constants: B=2, T=2048, C=1024, H=16, HS=64
typedef unsigned short u16;
typedef unsigned int u32;
typedef __bf16 bf16x8 __attribute__((ext_vector_type(8)));
typedef float f32x4 __attribute__((ext_vector_type(4)));
typedef u16 u16x4 __attribute__((ext_vector_type(4)));
typedef u16 u16x8 __attribute__((ext_vector_type(8)));

__device__ __forceinline__ u16 f2bf(float f) {
  u32 u = __builtin_bit_cast(u32, f);
  u += 0x7fffu + ((u >> 16) & 1u);   // round-to-nearest-even
  return (u16)(u >> 16);
}

__device__ __forceinline__ void gld16(const void* g, void* l) {
  __builtin_amdgcn_global_load_lds(
      (const __attribute__((address_space(1))) void*)g,
      (__attribute__((address_space(3))) void*)l, 16, 0, 0);
}

// ------------------------- prep kernels -------------------------
__global__ __launch_bounds__(256) void k_conv_x(const float* __restrict__ x,
                                                u16* __restrict__ xb) {
  int i = (blockIdx.x * 256 + threadIdx.x) * 4;
  float4 v = *(const float4*)(x + i);
  u16x4 o = { f2bf(v.x), f2bf(v.y), f2bf(v.z), f2bf(v.w) };
  *(u16x4*)(xb + i) = o;
}

// dst[Cc][R] (bf16) = transpose of src[R][Cc] (f32)
__global__ __launch_bounds__(256) void k_transpose(const float* __restrict__ src,
                                                   u16* __restrict__ dst,
                                                   int R, int Cc) {
  __shared__ float tile[32][33];
  int x = threadIdx.x & 31, y = threadIdx.x >> 5;
  int c0 = blockIdx.x * 32, r0 = blockIdx.y * 32;
  for (int i = 0; i < 4; ++i)
    tile[y + 8 * i][x] = src[(size_t)(r0 + y + 8 * i) * Cc + c0 + x];
  __syncthreads();
  for (int i = 0; i < 4; ++i)
    dst[(size_t)(c0 + y + 8 * i) * R + r0 + x] = f2bf(tile[x][y + 8 * i]);
}

// tab[t*32+d] = (cos, sin) of t * 10000^(-d/32)
__global__ __launch_bounds__(256) void k_rope_tab(float2* __restrict__ tab) {
  int i = blockIdx.x * 256 + threadIdx.x;  // 0..65535
  int t = i >> 5, d = i & 31;
  float theta = expf(-(float)d * 0.28782313662425575f);  // ln(10000)/32
  float ang = (float)t * theta;
  tab[i] = make_float2(cosf(ang), sinf(ang));
}

// --------------- QKV GEMM + bias + RoPE + scatter ---------------
// C[m][n] = Xb[m][:] . Wt[n][:],  m = b*2048+t, n = h*192 + p
// p<64: Q(hs=p)  64<=p<128: K(hs=p-64)  else V(hs=p-128)
// Epilogue: LDS-staged so all global stores are 16 B/lane coalesced.
// Note 192 = 3*64 and tiles are 128 = 2*64, so each 64-aligned n-halftile
// maps to exactly ONE region (Q|K|V) of ONE head -> wave-uniform routing.
__global__ __launch_bounds__(256) void k_qkv(
    const u16* __restrict__ Xb,      // [4096][1024] bf16
    const u16* __restrict__ Wt,      // [3072][1024] bf16 (W_qkv^T)
    const float* __restrict__ bias,  // [3072]
    const float2* __restrict__ rope, // [2048][32]
    u16* __restrict__ Qg,            // [B,H,T,HS]
    u16* __restrict__ Kg,            // [B,H,T,HS]
    u16* __restrict__ Vt) {          // [B,H,HS,T]
  __shared__ alignas(16) u16 As[128 * 32];
  __shared__ alignas(16) u16 Bs[128 * 32];
  __shared__ alignas(16) u16 Es[2][9216];  // epilogue staging, one per n-halftile
  const int tid = threadIdx.x;
  const int lane = tid & 63, w = tid >> 6;
  const int quad = lane >> 4, l15 = lane & 15;
  const int m0 = blockIdx.y * 128, n0 = blockIdx.x * 128;
  const int lr = lane >> 2, lc = (lane & 3) * 8;
  const int wm = (w & 1) * 64, wn = (w >> 1) * 64;
  const f32x4 vzero = {0.f, 0.f, 0.f, 0.f};

  f32x4 acc[4][4];
  for (int i = 0; i < 4; ++i)
    for (int j = 0; j < 4; ++j) acc[i][j] = vzero;

  for (int kt = 0; kt < 1024; kt += 32) {
    __syncthreads();
    for (int i = 0; i < 2; ++i) {
      int row = w * 32 + i * 16;
      gld16(Xb + (size_t)(m0 + row + lr) * 1024 + kt + lc, &As[row * 32]);
      gld16(Wt + (size_t)(n0 + row + lr) * 1024 + kt + lc, &Bs[row * 32]);
    }
    __syncthreads();
    bf16x8 a[4], b[4];
    for (int mt = 0; mt < 4; ++mt)
      a[mt] = *(const bf16x8*)&As[(wm + mt * 16 + l15) * 32 + quad * 8];
    for (int nt = 0; nt < 4; ++nt)
      b[nt] = *(const bf16x8*)&Bs[(wn + nt * 16 + l15) * 32 + quad * 8];
    for (int mt = 0; mt < 4; ++mt)
      for (int nt = 0; nt < 4; ++nt)
        acc[mt][nt] = __builtin_amdgcn_mfma_f32_16x16x32_bf16(
            a[mt], b[nt], acc[mt][nt], 0, 0, 0);
  }

  // ---- stage into LDS (bias + RoPE applied), wave-uniform region per half
  {
    const int half = w >> 1;             // waves 0,1 -> half 0; 2,3 -> half 1
    const int nh = n0 + half * 64;       // 64-aligned -> single region
    const int pbase = nh % 192;
    const int region = pbase >> 6;       // 0=Q 1=K 2=V
    for (int nt = 0; nt < 4; ++nt) {
      int c = nt * 16 + l15;             // 0..63 (== hs)
      float bv = bias[nh + c];
      for (int mt = 0; mt < 4; ++mt) {
        for (int r = 0; r < 4; ++r) {
          int m_l = wm + mt * 16 + quad * 4 + r;
          float v = acc[mt][nt][r] + bv;
          float partner = __shfl_xor(v, 1, 64);  // adjacent c = adjacent lane
          if (region < 2) {
            int t = (m0 + m_l) & 2047;
            float2 cs = rope[t * 32 + (c >> 1)];
            float outv = (c & 1) ? fmaf(partner, cs.y, v * cs.x)
                                 : fmaf(-partner, cs.y, v * cs.x);
            Es[half][m_l * 72 + c] = f2bf(outv);          // row-major, pad 72
          } else {
            Es[half][c * 136 + m_l] = f2bf(v);            // transposed, pad 136
          }
        }
      }
    }
  }
  __syncthreads();

  // ---- coalesced write-out: 16 B per lane
  const int bb = m0 >> 11, t0 = m0 & 2047;
  for (int hf = 0; hf < 2; ++hf) {
    const int nh = n0 + hf * 64;
    const int hh = nh / 192;
    const int region = (nh % 192) >> 6;
    if (region < 2) {
      u16* dst = (region == 0 ? Qg : Kg) +
                 ((size_t)(bb * 16 + hh) * 2048 + t0) * 64;
      int chunk = tid & 7, row0 = tid >> 3;
      for (int p = 0; p < 4; ++p) {
        int row = row0 + p * 32;
        u16x8 val = *(const u16x8*)&Es[hf][row * 72 + chunk * 8];
        *(u16x8*)(dst + (size_t)row * 64 + chunk * 8) = val;
      }
    } else {
      u16* dstv = Vt + (size_t)(bb * 16 + hh) * 64 * 2048 + t0;
      int mch = tid & 15, c0r = tid >> 4;
      for (int p = 0; p < 4; ++p) {
        int c = c0r + p * 16;
        u16x8 val = *(const u16x8*)&Es[hf][c * 136 + mch * 8];
        *(u16x8*)(dstv + (size_t)c * 2048 + mch * 8) = val;
      }
    }
  }
}

// ------------------- flash attention (causal) -------------------
// grid: (16 q-tiles, 32 bh). BQ=128, BKV=64. 4 waves, each owns 32 q-rows.
__global__ __launch_bounds__(256) void k_attn(
    const u16* __restrict__ Qg, const u16* __restrict__ Kg,
    const u16* __restrict__ Vt, u16* __restrict__ Og) {  // Og: [4096][1024] bf16
  __shared__ alignas(16) u16 Qs[128 * 64];
  __shared__ alignas(16) u16 Ks[64 * 64];
  __shared__ alignas(16) u16 Vs[64 * 64];   // [hs][kk]
  __shared__ alignas(16) u16 Ps[128 * 72];  // P main loop stride 64; epilogue stride 72
  const int tid = threadIdx.x, lane = tid & 63, w = tid >> 6;
  const int quad = lane >> 4, l15 = lane & 15;
  const int qt = 15 - blockIdx.x;  // heavy tiles first
  const int bh = blockIdx.y;
  const int q0 = qt * 128;
  const u16* Qh = Qg + (size_t)bh * 2048 * 64;
  const u16* Kh = Kg + (size_t)bh * 2048 * 64;
  const u16* Vh = Vt + (size_t)bh * 64 * 2048;
  const f32x4 vzero = {0.f, 0.f, 0.f, 0.f};
  const float LOG2E = 1.4426950408889634f;

  {  // stage Q tile once: 128x64
    int r8 = lane >> 3, c8 = (lane & 7) * 8;
    for (int i = 0; i < 4; ++i) {
      int row = w * 32 + i * 8;
      gld16(Qh + (size_t)(q0 + row + r8) * 64 + c8, &Qs[row * 64]);
    }
  }

  float mst[2][4], lst[2][4];
  f32x4 O[2][4];
  for (int mt = 0; mt < 2; ++mt)
    for (int r = 0; r < 4; ++r) { mst[mt][r] = -1e30f; lst[mt][r] = 0.f; }
  for (int mt = 0; mt < 2; ++mt)
    for (int nt = 0; nt < 4; ++nt) O[mt][nt] = vzero;

  const int nk = 2 * qt + 2;
  for (int kb = 0; kb < nk; ++kb) {
    int k0 = kb * 64;
    __syncthreads();  // prev tile's MFMAs done; also drains Q staging (vmcnt)
    {
      int r8 = lane >> 3, c8 = (lane & 7) * 8;
      for (int i = 0; i < 2; ++i) {
        int row = w * 16 + i * 8;
        gld16(Kh + (size_t)(k0 + row + r8) * 64 + c8, &Ks[row * 64]);
        gld16(Vh + (size_t)(row + r8) * 2048 + k0 + c8, &Vs[row * 64]);
      }
    }
    __syncthreads();

    // S = Q K^T for this wave's 32 rows x 64 cols
    f32x4 s[2][4];
    for (int mt = 0; mt < 2; ++mt)
      for (int nt = 0; nt < 4; ++nt) s[mt][nt] = vzero;
    for (int ks = 0; ks < 2; ++ks) {
      bf16x8 a[2], b[4];
      for (int mt = 0; mt < 2; ++mt)
        a[mt] = *(const bf16x8*)&Qs[(w * 32 + mt * 16 + l15) * 64 + ks * 32 + quad * 8];
      for (int nt = 0; nt < 4; ++nt)
        b[nt] = *(const bf16x8*)&Ks[(nt * 16 + l15) * 64 + ks * 32 + quad * 8];
      for (int mt = 0; mt < 2; ++mt)
        for (int nt = 0; nt < 4; ++nt)
          s[mt][nt] = __builtin_amdgcn_mfma_f32_16x16x32_bf16(a[mt], b[nt], s[mt][nt], 0, 0, 0);
    }

    // scale + causal mask + online softmax
    for (int mt = 0; mt < 2; ++mt) {
      for (int r = 0; r < 4; ++r) {
        int tq = q0 + w * 32 + mt * 16 + quad * 4 + r;
        float rmax = -1e30f;
        for (int nt = 0; nt < 4; ++nt) {
          int tk = k0 + nt * 16 + l15;
          float sv = s[mt][nt][r] * 0.125f;
          sv = (tk <= tq) ? sv : -1e30f;
          s[mt][nt][r] = sv;
          rmax = fmaxf(rmax, sv);
        }
        for (int msk = 1; msk < 16; msk <<= 1)
          rmax = fmaxf(rmax, __shfl_xor(rmax, msk, 64));
        float mold = mst[mt][r];
        float mnew = fmaxf(mold, rmax);
        float alpha = __builtin_amdgcn_exp2f((mold - mnew) * LOG2E);
        mst[mt][r] = mnew;
        float rsum = 0.f;
        for (int nt = 0; nt < 4; ++nt) {
          float pv = __builtin_amdgcn_exp2f((s[mt][nt][r] - mnew) * LOG2E);
          rsum += pv;
          Ps[(w * 32 + mt * 16 + quad * 4 + r) * 64 + nt * 16 + l15] = f2bf(pv);
        }
        for (int msk = 1; msk < 16; msk <<= 1)
          rsum += __shfl_xor(rsum, msk, 64);
        lst[mt][r] = lst[mt][r] * alpha + rsum;
        for (int nt2 = 0; nt2 < 4; ++nt2) O[mt][nt2][r] *= alpha;
      }
    }
    // Ps rows are wave-private in the main loop -> no barrier needed here.

    // O += P V  (K-dim = 64)
    for (int ks = 0; ks < 2; ++ks) {
      bf16x8 a[2], b[4];
      for (int mt = 0; mt < 2; ++mt)
        a[mt] = *(const bf16x8*)&Ps[(w * 32 + mt * 16 + l15) * 64 + ks * 32 + quad * 8];
      for (int nt = 0; nt < 4; ++nt)
        b[nt] = *(const bf16x8*)&Vs[(nt * 16 + l15) * 64 + ks * 32 + quad * 8];
      for (int mt = 0; mt < 2; ++mt)
        for (int nt = 0; nt < 4; ++nt)
          O[mt][nt] = __builtin_amdgcn_mfma_f32_16x16x32_bf16(a[mt], b[nt], O[mt][nt], 0, 0, 0);
    }
  }

  // epilogue: normalize, stage via Ps (stride 72), coalesced 16 B stores
  __syncthreads();  // everyone done with main-loop Ps/Vs use
  for (int mt = 0; mt < 2; ++mt)
    for (int nt = 0; nt < 4; ++nt)
      for (int r = 0; r < 4; ++r) {
        int row = w * 32 + mt * 16 + quad * 4 + r;
        Ps[row * 72 + nt * 16 + l15] = f2bf(O[mt][nt][r] / lst[mt][r]);
      }
  __syncthreads();
  const int bb = bh >> 4, h = bh & 15;
  u16* dst = Og + ((size_t)bb * 2048 + q0) * 1024 + h * 64;
  int chunk = tid & 7, row0 = tid >> 3;
  for (int p = 0; p < 4; ++p) {
    int row = row0 + p * 32;
    u16x8 val = *(const u16x8*)&Ps[row * 72 + chunk * 8];
    *(u16x8*)(dst + (size_t)row * 1024 + chunk * 8) = val;
  }
}

// --------------------- output projection GEMM ---------------------
__global__ __launch_bounds__(256) void k_proj(
    const u16* __restrict__ Ag,      // [4096][1024] bf16
    const u16* __restrict__ Wt,      // [1024][1024] bf16 (W_proj^T)
    const float* __restrict__ bias,  // [1024]
    float* __restrict__ out) {       // [4096][1024] f32
  __shared__ alignas(16) u16 As[128 * 32];
  __shared__ alignas(16) u16 Bs[128 * 32];
  const int tid = threadIdx.x;
  const int lane = tid & 63, w = tid >> 6;
  const int quad = lane >> 4, l15 = lane & 15;
  const int m0 = blockIdx.y * 128, n0 = blockIdx.x * 128;
  const int lr = lane >> 2, lc = (lane & 3) * 8;
  const int wm = (w & 1) * 64, wn = (w >> 1) * 64;
  const f32x4 vzero = {0.f, 0.f, 0.f, 0.f};

  f32x4 acc[4][4];
  for (int i = 0; i < 4; ++i)
    for (int j = 0; j < 4; ++j) acc[i][j] = vzero;

  for (int kt = 0; kt < 1024; kt += 32) {
    __syncthreads();
    for (int i = 0; i < 2; ++i) {
      int row = w * 32 + i * 16;
      gld16(Ag + (size_t)(m0 + row + lr) * 1024 + kt + lc, &As[row * 32]);
      gld16(Wt + (size_t)(n0 + row + lr) * 1024 + kt + lc, &Bs[row * 32]);
    }
    __syncthreads();
    bf16x8 a[4], b[4];
    for (int mt = 0; mt < 4; ++mt)
      a[mt] = *(const bf16x8*)&As[(wm + mt * 16 + l15) * 32 + quad * 8];
    for (int nt = 0; nt < 4; ++nt)
      b[nt] = *(const bf16x8*)&Bs[(wn + nt * 16 + l15) * 32 + quad * 8];
    for (int mt = 0; mt < 4; ++mt)
      for (int nt = 0; nt < 4; ++nt)
        acc[mt][nt] = __builtin_amdgcn_mfma_f32_16x16x32_bf16(
            a[mt], b[nt], acc[mt][nt], 0, 0, 0);
  }

  // f32 stores: 16 lanes x 4 B = 64 B contiguous per quad-row -> full sectors
  for (int nt = 0; nt < 4; ++nt) {
    int n = n0 + wn + nt * 16 + l15;
    float bv = bias[n];
    for (int mt = 0; mt < 4; ++mt)
      for (int r = 0; r < 4; ++r) {
        int m = m0 + wm + mt * 16 + quad * 4 + r;
        out[(size_t)m * 1024 + n] = acc[mt][nt][r] + bv;
      }
  }
}

extern "C" void kernel_launch(void* const* d_in, const int* in_sizes, int n_in,
                              void* d_out, int out_size, void* d_ws, size_t ws_size,
                              hipStream_t stream) {
  (void)in_sizes; (void)n_in; (void)out_size; (void)ws_size;
  const float* x     = (const float*)d_in[0];
  const float* Wqkv  = (const float*)d_in[1];
  const float* bqkv  = (const float*)d_in[2];
  const float* Wproj = (const float*)d_in[3];
  const float* bproj = (const float*)d_in[4];
  float* out = (float*)d_out;

  char* ws = (char*)d_ws;
  size_t off = 0;
  u16* Xb    = (u16*)(ws + off); off += (size_t)4096 * 1024 * 2;   // x bf16
  u16* Wqkvt = (u16*)(ws + off); off += (size_t)3072 * 1024 * 2;   // W_qkv^T bf16
  u16* Wpt   = (u16*)(ws + off); off += (size_t)1024 * 1024 * 2;   // W_proj^T bf16
  u16* Qg    = (u16*)(ws + off); off += (size_t)2 * 16 * 2048 * 64 * 2;
  u16* Kg    = (u16*)(ws + off); off += (size_t)2 * 16 * 2048 * 64 * 2;
  u16* Vt    = (u16*)(ws + off); off += (size_t)2 * 16 * 64 * 2048 * 2;
  u16* Att   = (u16*)(ws + off); off += (size_t)4096 * 1024 * 2;
  float2* rope = (float2*)(ws + off); off += (size_t)2048 * 32 * sizeof(float2);

  k_conv_x<<<4096, 256, 0, stream>>>(x, Xb);
  k_transpose<<<dim3(96, 32), 256, 0, stream>>>(Wqkv, Wqkvt, 1024, 3072);
  k_transpose<<<dim3(32, 32), 256, 0, stream>>>(Wproj, Wpt, 1024, 1024);
  k_rope_tab<<<256, 256, 0, stream>>>(rope);
  k_qkv<<<dim3(24, 32), 256, 0, stream>>>(Xb, Wqkvt, bqkv, rope, Qg, Kg, Vt);
  k_attn<<<dim3(16, 32), 256, 0, stream>>>(Qg, Kg, Vt, Att);
  k_proj<<<dim3(8, 32), 256, 0, stream>>>(Att, Wpt, bproj, out);
}

// Round 3
// 206.837 us; speedup vs baseline: 2.5124x; 1.4942x over previous
//
#include <hip/hip_runtime.h>

// Problem constants: B=2, T=2048, C=1024, H=16, HS=64
typedef unsigned short u16;
typedef unsigned int u32;
typedef __bf16 bf16x8 __attribute__((ext_vector_type(8)));
typedef float f32x4 __attribute__((ext_vector_type(4)));
typedef u16 u16x4 __attribute__((ext_vector_type(4)));
typedef u16 u16x8 __attribute__((ext_vector_type(8)));

__device__ __forceinline__ u16 f2bf(float f) {
  u32 u = __builtin_bit_cast(u32, f);
  u += 0x7fffu + ((u >> 16) & 1u);   // round-to-nearest-even
  return (u16)(u >> 16);
}

__device__ __forceinline__ void gld16(const void* g, void* l) {
  __builtin_amdgcn_global_load_lds(
      (const __attribute__((address_space(1))) void*)g,
      (__attribute__((address_space(3))) void*)l, 16, 0, 0);
}

// ------------------------- prep kernels -------------------------
__global__ __launch_bounds__(256) void k_conv_x(const float* __restrict__ x,
                                                u16* __restrict__ xb) {
  int i = (blockIdx.x * 256 + threadIdx.x) * 4;
  float4 v = *(const float4*)(x + i);
  u16x4 o = { f2bf(v.x), f2bf(v.y), f2bf(v.z), f2bf(v.w) };
  *(u16x4*)(xb + i) = o;
}

// dst[Cc][R] (bf16) = transpose of src[R][Cc] (f32)
__global__ __launch_bounds__(256) void k_transpose(const float* __restrict__ src,
                                                   u16* __restrict__ dst,
                                                   int R, int Cc) {
  __shared__ float tile[32][33];
  int x = threadIdx.x & 31, y = threadIdx.x >> 5;
  int c0 = blockIdx.x * 32, r0 = blockIdx.y * 32;
  for (int i = 0; i < 4; ++i)
    tile[y + 8 * i][x] = src[(size_t)(r0 + y + 8 * i) * Cc + c0 + x];
  __syncthreads();
  for (int i = 0; i < 4; ++i)
    dst[(size_t)(c0 + y + 8 * i) * R + r0 + x] = f2bf(tile[x][y + 8 * i]);
}

// tab[t*32+d] = (cos, sin) of t * 10000^(-d/32)
__global__ __launch_bounds__(256) void k_rope_tab(float2* __restrict__ tab) {
  int i = blockIdx.x * 256 + threadIdx.x;  // 0..65535
  int t = i >> 5, d = i & 31;
  float theta = expf(-(float)d * 0.28782313662425575f);  // ln(10000)/32
  float ang = (float)t * theta;
  tab[i] = make_float2(cosf(ang), sinf(ang));
}

// --------------- QKV GEMM + bias + RoPE + scatter ---------------
__global__ __launch_bounds__(256) void k_qkv(
    const u16* __restrict__ Xb,      // [4096][1024] bf16
    const u16* __restrict__ Wt,      // [3072][1024] bf16 (W_qkv^T)
    const float* __restrict__ bias,  // [3072]
    const float2* __restrict__ rope, // [2048][32]
    u16* __restrict__ Qg,            // [B,H,T,HS]
    u16* __restrict__ Kg,            // [B,H,T,HS]
    u16* __restrict__ Vt) {          // [B,H,HS,T]
  __shared__ alignas(16) u16 As[128 * 32];
  __shared__ alignas(16) u16 Bs[128 * 32];
  __shared__ alignas(16) u16 Es[2][9216];  // epilogue staging, one per n-halftile
  const int tid = threadIdx.x;
  const int lane = tid & 63, w = tid >> 6;
  const int quad = lane >> 4, l15 = lane & 15;
  const int m0 = blockIdx.y * 128, n0 = blockIdx.x * 128;
  const int lr = lane >> 2, lc = (lane & 3) * 8;
  const int wm = (w & 1) * 64, wn = (w >> 1) * 64;
  const f32x4 vzero = {0.f, 0.f, 0.f, 0.f};

  f32x4 acc[4][4];
  for (int i = 0; i < 4; ++i)
    for (int j = 0; j < 4; ++j) acc[i][j] = vzero;

  for (int kt = 0; kt < 1024; kt += 32) {
    __syncthreads();
    for (int i = 0; i < 2; ++i) {
      int row = w * 32 + i * 16;
      gld16(Xb + (size_t)(m0 + row + lr) * 1024 + kt + lc, &As[row * 32]);
      gld16(Wt + (size_t)(n0 + row + lr) * 1024 + kt + lc, &Bs[row * 32]);
    }
    __syncthreads();
    bf16x8 a[4], b[4];
    for (int mt = 0; mt < 4; ++mt)
      a[mt] = *(const bf16x8*)&As[(wm + mt * 16 + l15) * 32 + quad * 8];
    for (int nt = 0; nt < 4; ++nt)
      b[nt] = *(const bf16x8*)&Bs[(wn + nt * 16 + l15) * 32 + quad * 8];
    for (int mt = 0; mt < 4; ++mt)
      for (int nt = 0; nt < 4; ++nt)
        acc[mt][nt] = __builtin_amdgcn_mfma_f32_16x16x32_bf16(
            a[mt], b[nt], acc[mt][nt], 0, 0, 0);
  }

  // ---- stage into LDS (bias + RoPE applied), wave-uniform region per half
  {
    const int half = w >> 1;
    const int nh = n0 + half * 64;       // 64-aligned -> single region
    const int pbase = nh % 192;
    const int region = pbase >> 6;       // 0=Q 1=K 2=V
    for (int nt = 0; nt < 4; ++nt) {
      int c = nt * 16 + l15;             // 0..63 (== hs)
      float bv = bias[nh + c];
      for (int mt = 0; mt < 4; ++mt) {
        for (int r = 0; r < 4; ++r) {
          int m_l = wm + mt * 16 + quad * 4 + r;
          float v = acc[mt][nt][r] + bv;
          float partner = __shfl_xor(v, 1, 64);  // adjacent c = adjacent lane
          if (region < 2) {
            int t = (m0 + m_l) & 2047;
            float2 cs = rope[t * 32 + (c >> 1)];
            float outv = (c & 1) ? fmaf(partner, cs.y, v * cs.x)
                                 : fmaf(-partner, cs.y, v * cs.x);
            Es[half][m_l * 72 + c] = f2bf(outv);          // row-major, pad 72
          } else {
            Es[half][c * 136 + m_l] = f2bf(v);            // transposed, pad 136
          }
        }
      }
    }
  }
  __syncthreads();

  // ---- coalesced write-out: 16 B per lane
  const int bb = m0 >> 11, t0 = m0 & 2047;
  for (int hf = 0; hf < 2; ++hf) {
    const int nh = n0 + hf * 64;
    const int hh = nh / 192;
    const int region = (nh % 192) >> 6;
    if (region < 2) {
      u16* dst = (region == 0 ? Qg : Kg) +
                 ((size_t)(bb * 16 + hh) * 2048 + t0) * 64;
      int chunk = tid & 7, row0 = tid >> 3;
      for (int p = 0; p < 4; ++p) {
        int row = row0 + p * 32;
        u16x8 val = *(const u16x8*)&Es[hf][row * 72 + chunk * 8];
        *(u16x8*)(dst + (size_t)row * 64 + chunk * 8) = val;
      }
    } else {
      u16* dstv = Vt + (size_t)(bb * 16 + hh) * 64 * 2048 + t0;
      int mch = tid & 15, c0r = tid >> 4;
      for (int p = 0; p < 4; ++p) {
        int c = c0r + p * 16;
        u16x8 val = *(const u16x8*)&Es[hf][c * 136 + mch * 8];
        *(u16x8*)(dstv + (size_t)c * 2048 + mch * 8) = val;
      }
    }
  }
}

// ------------------- flash attention (causal) -------------------
// grid: (16, 32 bh), 512 threads = 8 waves. BQ=128, BKV=64.
// Wave w owns q-rows [w*16, w*16+16). Q a-frags live in registers.
// Ks/Vs are XOR-chunk-swizzled (swizzle applied on the gld16 global source);
// Ps padded to stride 72 u16 (144 B, 16B-aligned). No-max softmax (scores
// provably bounded << fp32 exp range); l reduced once at the end.
__global__ __launch_bounds__(512, 4) void k_attn(
    const u16* __restrict__ Qg, const u16* __restrict__ Kg,
    const u16* __restrict__ Vt, u16* __restrict__ Og) {  // Og: [4096][1024] bf16
  __shared__ alignas(16) u16 Ks[64 * 64];
  __shared__ alignas(16) u16 Vs[64 * 64];    // [hs][kk]
  __shared__ alignas(16) u16 Ps[128 * 72];
  const int tid = threadIdx.x, lane = tid & 63, w = tid >> 6;
  const int quad = lane >> 4, l15 = lane & 15;
  const int bh = blockIdx.y;
  // complementary-pairing hash: blocks c and c+256 (same CU under round-robin)
  // get q-tiles summing to 15 -> near-constant per-CU work
  int tmp = (blockIdx.x + bh) & 15;
  const int qt = (bh & 16) ? (15 - tmp) : tmp;
  const int q0 = qt * 128;
  const u16* Qh = Qg + (size_t)bh * 2048 * 64;
  const u16* Kh = Kg + (size_t)bh * 2048 * 64;
  const u16* Vh = Vt + (size_t)bh * 64 * 2048;
  const f32x4 vzero = {0.f, 0.f, 0.f, 0.f};
  const float SCL = 0.125f * 1.4426950408889634f;  // 1/sqrt(64) * log2(e)

  // Q fragments direct to registers (row = q0 + w*16 + l15)
  bf16x8 aq[2];
  {
    const u16* qp = Qh + (size_t)(q0 + w * 16 + l15) * 64 + quad * 8;
    aq[0] = *(const bf16x8*)(qp);
    aq[1] = *(const bf16x8*)(qp + 32);
  }

  // staging source swizzle: lane (r8,j) fetches global chunk j^r8 of its row
  const int r8 = lane >> 3, j8 = lane & 7;
  const int sw_c = (j8 ^ r8) * 8;  // swizzled u16 col offset

  float lsum[4] = {0.f, 0.f, 0.f, 0.f};
  f32x4 O[4];
  for (int nt = 0; nt < 4; ++nt) O[nt] = vzero;

  const int nk = 2 * qt + 2;
  for (int kb = 0; kb < nk; ++kb) {
    int k0 = kb * 64;
    __syncthreads();  // previous tile's LDS reads complete
    gld16(Kh + (size_t)(k0 + w * 8 + r8) * 64 + sw_c, &Ks[w * 8 * 64]);
    gld16(Vh + (size_t)(w * 8 + r8) * 2048 + k0 + sw_c, &Vs[w * 8 * 64]);
    __syncthreads();  // drains vmcnt -> staged data visible

    if (k0 <= q0 + w * 16 + 15) {  // wave-uniform: skip fully-masked blocks
      // S = Q K^T : 16 rows x 64 cols per wave
      f32x4 s[4];
      for (int nt = 0; nt < 4; ++nt) s[nt] = vzero;
      for (int ks = 0; ks < 2; ++ks) {
        bf16x8 b[4];
        for (int nt = 0; nt < 4; ++nt)
          b[nt] = *(const bf16x8*)&Ks[(nt * 16 + l15) * 64 +
                                      ((ks * 4 + quad) ^ (l15 & 7)) * 8];
        for (int nt = 0; nt < 4; ++nt)
          s[nt] = __builtin_amdgcn_mfma_f32_16x16x32_bf16(aq[ks], b[nt], s[nt], 0, 0, 0);
      }

      // no-max softmax: p = exp2(s * SCL); mask only in partial blocks
      const bool anymask = (k0 + 63 > q0 + w * 16);
      for (int r = 0; r < 4; ++r) {
        int prow = w * 16 + quad * 4 + r;
        int tq = q0 + prow;
        float acc_l = 0.f;
        for (int nt = 0; nt < 4; ++nt) {
          float pv = __builtin_amdgcn_exp2f(s[nt][r] * SCL);
          if (anymask && (k0 + nt * 16 + l15 > tq)) pv = 0.f;
          acc_l += pv;
          Ps[prow * 72 + nt * 16 + l15] = f2bf(pv);
        }
        lsum[r] += acc_l;
      }

      // O += P V
      for (int ks = 0; ks < 2; ++ks) {
        bf16x8 a = *(const bf16x8*)&Ps[(w * 16 + l15) * 72 + ks * 32 + quad * 8];
        bf16x8 b[4];
        for (int nt = 0; nt < 4; ++nt)
          b[nt] = *(const bf16x8*)&Vs[(nt * 16 + l15) * 64 +
                                      ((ks * 4 + quad) ^ (l15 & 7)) * 8];
        for (int nt = 0; nt < 4; ++nt)
          O[nt] = __builtin_amdgcn_mfma_f32_16x16x32_bf16(a, b[nt], O[nt], 0, 0, 0);
      }
    }
  }

  // single deferred l reduction (within 16-lane groups)
  float inv[4];
  for (int r = 0; r < 4; ++r) {
    float v = lsum[r];
    for (int msk = 1; msk < 16; msk <<= 1) v += __shfl_xor(v, msk, 64);
    inv[r] = 1.0f / v;
  }

  // epilogue: normalize, stage via Ps (stride 72), coalesced 16 B stores
  __syncthreads();
  for (int nt = 0; nt < 4; ++nt)
    for (int r = 0; r < 4; ++r)
      Ps[(w * 16 + quad * 4 + r) * 72 + nt * 16 + l15] = f2bf(O[nt][r] * inv[r]);
  __syncthreads();
  const int bb = bh >> 4, h = bh & 15;
  u16* dst = Og + ((size_t)bb * 2048 + q0) * 1024 + h * 64;
  int chunk = tid & 7, row0 = tid >> 3;
  for (int p = 0; p < 2; ++p) {
    int row = row0 + p * 64;
    u16x8 val = *(const u16x8*)&Ps[row * 72 + chunk * 8];
    *(u16x8*)(dst + (size_t)row * 1024 + chunk * 8) = val;
  }
}

// --------------------- output projection GEMM ---------------------
__global__ __launch_bounds__(256) void k_proj(
    const u16* __restrict__ Ag,      // [4096][1024] bf16
    const u16* __restrict__ Wt,      // [1024][1024] bf16 (W_proj^T)
    const float* __restrict__ bias,  // [1024]
    float* __restrict__ out) {       // [4096][1024] f32
  __shared__ alignas(16) u16 As[128 * 32];
  __shared__ alignas(16) u16 Bs[128 * 32];
  const int tid = threadIdx.x;
  const int lane = tid & 63, w = tid >> 6;
  const int quad = lane >> 4, l15 = lane & 15;
  const int m0 = blockIdx.y * 128, n0 = blockIdx.x * 128;
  const int lr = lane >> 2, lc = (lane & 3) * 8;
  const int wm = (w & 1) * 64, wn = (w >> 1) * 64;
  const f32x4 vzero = {0.f, 0.f, 0.f, 0.f};

  f32x4 acc[4][4];
  for (int i = 0; i < 4; ++i)
    for (int j = 0; j < 4; ++j) acc[i][j] = vzero;

  for (int kt = 0; kt < 1024; kt += 32) {
    __syncthreads();
    for (int i = 0; i < 2; ++i) {
      int row = w * 32 + i * 16;
      gld16(Ag + (size_t)(m0 + row + lr) * 1024 + kt + lc, &As[row * 32]);
      gld16(Wt + (size_t)(n0 + row + lr) * 1024 + kt + lc, &Bs[row * 32]);
    }
    __syncthreads();
    bf16x8 a[4], b[4];
    for (int mt = 0; mt < 4; ++mt)
      a[mt] = *(const bf16x8*)&As[(wm + mt * 16 + l15) * 32 + quad * 8];
    for (int nt = 0; nt < 4; ++nt)
      b[nt] = *(const bf16x8*)&Bs[(wn + nt * 16 + l15) * 32 + quad * 8];
    for (int mt = 0; mt < 4; ++mt)
      for (int nt = 0; nt < 4; ++nt)
        acc[mt][nt] = __builtin_amdgcn_mfma_f32_16x16x32_bf16(
            a[mt], b[nt], acc[mt][nt], 0, 0, 0);
  }

  for (int nt = 0; nt < 4; ++nt) {
    int n = n0 + wn + nt * 16 + l15;
    float bv = bias[n];
    for (int mt = 0; mt < 4; ++mt)
      for (int r = 0; r < 4; ++r) {
        int m = m0 + wm + mt * 16 + quad * 4 + r;
        out[(size_t)m * 1024 + n] = acc[mt][nt][r] + bv;
      }
  }
}

extern "C" void kernel_launch(void* const* d_in, const int* in_sizes, int n_in,
                              void* d_out, int out_size, void* d_ws, size_t ws_size,
                              hipStream_t stream) {
  (void)in_sizes; (void)n_in; (void)out_size; (void)ws_size;
  const float* x     = (const float*)d_in[0];
  const float* Wqkv  = (const float*)d_in[1];
  const float* bqkv  = (const float*)d_in[2];
  const float* Wproj = (const float*)d_in[3];
  const float* bproj = (const float*)d_in[4];
  float* out = (float*)d_out;

  char* ws = (char*)d_ws;
  size_t off = 0;
  u16* Xb    = (u16*)(ws + off); off += (size_t)4096 * 1024 * 2;   // x bf16
  u16* Wqkvt = (u16*)(ws + off); off += (size_t)3072 * 1024 * 2;   // W_qkv^T bf16
  u16* Wpt   = (u16*)(ws + off); off += (size_t)1024 * 1024 * 2;   // W_proj^T bf16
  u16* Qg    = (u16*)(ws + off); off += (size_t)2 * 16 * 2048 * 64 * 2;
  u16* Kg    = (u16*)(ws + off); off += (size_t)2 * 16 * 2048 * 64 * 2;
  u16* Vt    = (u16*)(ws + off); off += (size_t)2 * 16 * 64 * 2048 * 2;
  u16* Att   = (u16*)(ws + off); off += (size_t)4096 * 1024 * 2;
  float2* rope = (float2*)(ws + off); off += (size_t)2048 * 32 * sizeof(float2);

  k_conv_x<<<4096, 256, 0, stream>>>(x, Xb);
  k_transpose<<<dim3(96, 32), 256, 0, stream>>>(Wqkv, Wqkvt, 1024, 3072);
  k_transpose<<<dim3(32, 32), 256, 0, stream>>>(Wproj, Wpt, 1024, 1024);
  k_rope_tab<<<256, 256, 0, stream>>>(rope);
  k_qkv<<<dim3(24, 32), 256, 0, stream>>>(Xb, Wqkvt, bqkv, rope, Qg, Kg, Vt);
  k_attn<<<dim3(16, 32), 512, 0, stream>>>(Qg, Kg, Vt, Att);
  k_proj<<<dim3(8, 32), 256, 0, stream>>>(Att, Wpt, bproj, out);
}

// Round 4
// 196.588 us; speedup vs baseline: 2.6434x; 1.0521x over previous
//
#include <hip/hip_runtime.h>

// Problem constants: B=2, T=2048, C=1024, H=16, HS=64
typedef unsigned short u16;
typedef unsigned int u32;
typedef __bf16 bf16x8 __attribute__((ext_vector_type(8)));
typedef float f32x4 __attribute__((ext_vector_type(4)));
typedef u16 u16x4 __attribute__((ext_vector_type(4)));
typedef u16 u16x8 __attribute__((ext_vector_type(8)));

__device__ __forceinline__ u16 f2bf(float f) {
  u32 u = __builtin_bit_cast(u32, f);
  u += 0x7fffu + ((u >> 16) & 1u);   // round-to-nearest-even
  return (u16)(u >> 16);
}

// pack two f32 -> two bf16 (round-half-up) in one u32; a in low half.
__device__ __forceinline__ u32 pk2(float a, float b) {
  u32 ua = __builtin_bit_cast(u32, a) + 0x8000u;
  u32 ub = __builtin_bit_cast(u32, b) + 0x8000u;
  return __builtin_amdgcn_perm(ub, ua, 0x07060302);  // {ub.hi16, ua.hi16}
}

__device__ __forceinline__ void gld16(const void* g, void* l) {
  __builtin_amdgcn_global_load_lds(
      (const __attribute__((address_space(1))) void*)g,
      (__attribute__((address_space(3))) void*)l, 16, 0, 0);
}

// ---------------- merged prep kernel (one launch) ----------------
// blocks [0,4096): x -> bf16
// blocks [4096,7168): transpose Wqkv (1024x3072) -> bf16 [3072][1024]
// blocks [7168,8192): transpose Wproj (1024x1024) -> bf16 [1024][1024]
// blocks [8192,8448): rope table
__global__ __launch_bounds__(256) void k_prep(
    const float* __restrict__ x, u16* __restrict__ xb,
    const float* __restrict__ Wqkv, u16* __restrict__ Wqkvt,
    const float* __restrict__ Wproj, u16* __restrict__ Wpt,
    float2* __restrict__ rope) {
  __shared__ float tile[32][33];
  const int tid = threadIdx.x;
  int bx = blockIdx.x;
  if (bx < 4096) {
    int i = (bx * 256 + tid) * 4;
    float4 v = *(const float4*)(x + i);
    u16x4 o = { f2bf(v.x), f2bf(v.y), f2bf(v.z), f2bf(v.w) };
    *(u16x4*)(xb + i) = o;
    return;
  }
  bx -= 4096;
  const float* src; u16* dst; int R, Cc, bxx, byy;
  if (bx < 3072) {
    src = Wqkv; dst = Wqkvt; R = 1024; Cc = 3072; bxx = bx % 96; byy = bx / 96;
  } else if (bx < 4096) {
    int b = bx - 3072;
    src = Wproj; dst = Wpt; R = 1024; Cc = 1024; bxx = b % 32; byy = b / 32;
  } else {
    int i = (bx - 4096) * 256 + tid;  // 0..65535
    int t = i >> 5, d = i & 31;
    float theta = expf(-(float)d * 0.28782313662425575f);  // ln(10000)/32
    float ang = (float)t * theta;
    rope[i] = make_float2(cosf(ang), sinf(ang));
    return;
  }
  int xx = tid & 31, yy = tid >> 5;
  int c0 = bxx * 32, r0 = byy * 32;
  for (int i = 0; i < 4; ++i)
    tile[yy + 8 * i][xx] = src[(size_t)(r0 + yy + 8 * i) * Cc + c0 + xx];
  __syncthreads();
  for (int i = 0; i < 4; ++i)
    dst[(size_t)(c0 + yy + 8 * i) * R + r0 + xx] = f2bf(tile[xx][yy + 8 * i]);
}

// --------------- QKV GEMM + bias + RoPE + scatter ---------------
__global__ __launch_bounds__(256) void k_qkv(
    const u16* __restrict__ Xb,      // [4096][1024] bf16
    const u16* __restrict__ Wt,      // [3072][1024] bf16 (W_qkv^T)
    const float* __restrict__ bias,  // [3072]
    const float2* __restrict__ rope, // [2048][32]
    u16* __restrict__ Qg,            // [B,H,T,HS]
    u16* __restrict__ Kg,            // [B,H,T,HS]
    u16* __restrict__ Vt) {          // [B,H,HS,T]
  __shared__ alignas(16) u16 As[128 * 32];
  __shared__ alignas(16) u16 Bs[128 * 32];
  __shared__ alignas(16) u16 Es[2][9216];  // epilogue staging, one per n-halftile
  const int tid = threadIdx.x;
  const int lane = tid & 63, w = tid >> 6;
  const int quad = lane >> 4, l15 = lane & 15;
  const int m0 = blockIdx.y * 128, n0 = blockIdx.x * 128;
  const int lr = lane >> 2, lc = (lane & 3) * 8;
  const int wm = (w & 1) * 64, wn = (w >> 1) * 64;
  const f32x4 vzero = {0.f, 0.f, 0.f, 0.f};

  f32x4 acc[4][4];
  for (int i = 0; i < 4; ++i)
    for (int j = 0; j < 4; ++j) acc[i][j] = vzero;

  for (int kt = 0; kt < 1024; kt += 32) {
    __syncthreads();
    for (int i = 0; i < 2; ++i) {
      int row = w * 32 + i * 16;
      gld16(Xb + (size_t)(m0 + row + lr) * 1024 + kt + lc, &As[row * 32]);
      gld16(Wt + (size_t)(n0 + row + lr) * 1024 + kt + lc, &Bs[row * 32]);
    }
    __syncthreads();
    bf16x8 a[4], b[4];
    for (int mt = 0; mt < 4; ++mt)
      a[mt] = *(const bf16x8*)&As[(wm + mt * 16 + l15) * 32 + quad * 8];
    for (int nt = 0; nt < 4; ++nt)
      b[nt] = *(const bf16x8*)&Bs[(wn + nt * 16 + l15) * 32 + quad * 8];
    for (int mt = 0; mt < 4; ++mt)
      for (int nt = 0; nt < 4; ++nt)
        acc[mt][nt] = __builtin_amdgcn_mfma_f32_16x16x32_bf16(
            a[mt], b[nt], acc[mt][nt], 0, 0, 0);
  }

  // ---- stage into LDS (bias + RoPE applied), wave-uniform region per half
  {
    const int half = w >> 1;
    const int nh = n0 + half * 64;       // 64-aligned -> single region
    const int region = (nh % 192) >> 6;  // 0=Q 1=K 2=V
    if (region < 2) {
      for (int nt = 0; nt < 4; ++nt) {
        int c = nt * 16 + l15;           // 0..63 (== hs)
        float bv = bias[nh + c];
        for (int mt = 0; mt < 4; ++mt) {
          for (int r = 0; r < 4; ++r) {
            int m_l = wm + mt * 16 + quad * 4 + r;
            float v = acc[mt][nt][r] + bv;
            float partner = __shfl_xor(v, 1, 64);  // adjacent c = adjacent lane
            int t = (m0 + m_l) & 2047;
            float2 cs = rope[t * 32 + (c >> 1)];
            float outv = (c & 1) ? fmaf(partner, cs.y, v * cs.x)
                                 : fmaf(-partner, cs.y, v * cs.x);
            Es[half][m_l * 72 + c] = f2bf(outv);          // row-major, pad 72
          }
        }
      }
    } else {
      for (int nt = 0; nt < 4; ++nt) {
        int c = nt * 16 + l15;
        float bv = bias[nh + c];
        for (int mt = 0; mt < 4; ++mt) {
          float v0 = acc[mt][nt][0] + bv, v1 = acc[mt][nt][1] + bv;
          float v2 = acc[mt][nt][2] + bv, v3 = acc[mt][nt][3] + bv;
          uint2 pv; pv.x = pk2(v0, v1); pv.y = pk2(v2, v3);
          // transposed [c][m], r-values are consecutive m -> one b64 write
          *(uint2*)&Es[half][c * 136 + wm + mt * 16 + quad * 4] = pv;
        }
      }
    }
  }
  __syncthreads();

  // ---- coalesced write-out: 16 B per lane
  const int bb = m0 >> 11, t0 = m0 & 2047;
  for (int hf = 0; hf < 2; ++hf) {
    const int nh = n0 + hf * 64;
    const int hh = nh / 192;
    const int region = (nh % 192) >> 6;
    if (region < 2) {
      u16* dst = (region == 0 ? Qg : Kg) +
                 ((size_t)(bb * 16 + hh) * 2048 + t0) * 64;
      int chunk = tid & 7, row0 = tid >> 3;
      for (int p = 0; p < 4; ++p) {
        int row = row0 + p * 32;
        u16x8 val = *(const u16x8*)&Es[hf][row * 72 + chunk * 8];
        *(u16x8*)(dst + (size_t)row * 64 + chunk * 8) = val;
      }
    } else {
      u16* dstv = Vt + (size_t)(bb * 16 + hh) * 64 * 2048 + t0;
      int mch = tid & 15, c0r = tid >> 4;
      for (int p = 0; p < 4; ++p) {
        int c = c0r + p * 16;
        u16x8 val = *(const u16x8*)&Es[hf][c * 136 + mch * 8];
        *(u16x8*)(dstv + (size_t)c * 2048 + mch * 8) = val;
      }
    }
  }
}

// ------------------- flash attention (causal) -------------------
// grid: (16, 32 bh), 512 threads = 8 waves. BQ=128, BKV=64, K/V double-buffered.
// Computes S^T = K·Q^T (operand swap is free: A/B frags have identical per-lane
// patterns), so each lane holds 4 consecutive k for one q -> packed b64 P-writes.
// No-max softmax (scores bounded << fp32 exp range); l reduced once at the end.
__global__ __launch_bounds__(512, 4) void k_attn(
    const u16* __restrict__ Qg, const u16* __restrict__ Kg,
    const u16* __restrict__ Vt, u16* __restrict__ Og) {  // Og: [4096][1024] bf16
  __shared__ alignas(16) u16 Ks[2][64 * 64];
  __shared__ alignas(16) u16 Vs[2][64 * 64];   // [hs][kk]
  __shared__ alignas(16) u16 Ps[128 * 72];
  const int tid = threadIdx.x, lane = tid & 63, w = tid >> 6;
  const int quad = lane >> 4, l15 = lane & 15;
  const int bh = blockIdx.y;
  // complementary-pairing hash: near-constant per-CU work
  int tmp = (blockIdx.x + bh) & 15;
  const int qt = (bh & 16) ? (15 - tmp) : tmp;
  const int q0 = qt * 128;
  const u16* Qh = Qg + (size_t)bh * 2048 * 64;
  const u16* Kh = Kg + (size_t)bh * 2048 * 64;
  const u16* Vh = Vt + (size_t)bh * 64 * 2048;
  const f32x4 vzero = {0.f, 0.f, 0.f, 0.f};
  const float SCL = 0.125f * 1.4426950408889634f;  // 1/sqrt(64) * log2(e)
  const int myrow = w * 16;

  // Q fragments direct to registers (row = q0 + myrow + l15)
  bf16x8 aq[2];
  {
    const u16* qp = Qh + (size_t)(q0 + myrow + l15) * 64 + quad * 8;
    aq[0] = *(const bf16x8*)(qp);
    aq[1] = *(const bf16x8*)(qp + 32);
  }

  // staging source swizzle: lane (r8,j) fetches global chunk j^r8 of its row
  const int r8 = lane >> 3, j8 = lane & 7;
  const int sw_c = (j8 ^ r8) * 8;

  float lsum = 0.f;
  f32x4 O[4];
  for (int nt = 0; nt < 4; ++nt) O[nt] = vzero;

  const int nk = 2 * qt + 2;
  // prologue: stage kb=0 into buffer 0
  gld16(Kh + (size_t)(w * 8 + r8) * 64 + sw_c, &Ks[0][w * 8 * 64]);
  gld16(Vh + (size_t)(w * 8 + r8) * 2048 + sw_c, &Vs[0][w * 8 * 64]);

  for (int kb = 0; kb < nk; ++kb) {
    const int k0 = kb * 64;
    const int cur = kb & 1;
    __syncthreads();  // buf[cur] staged+visible; buf[cur^1] readers (kb-1) done
    if (kb + 1 < nk) {
      const int k1 = k0 + 64;
      gld16(Kh + (size_t)(k1 + w * 8 + r8) * 64 + sw_c, &Ks[cur ^ 1][w * 8 * 64]);
      gld16(Vh + (size_t)(w * 8 + r8) * 2048 + k1 + sw_c, &Vs[cur ^ 1][w * 8 * 64]);
    }
    if (k0 > q0 + myrow + 15) continue;  // wave-uniform: fully masked

    // S^T = K Q^T : rows = k (64), cols = q (this wave's 16)
    f32x4 st[4];
    for (int nt = 0; nt < 4; ++nt) st[nt] = vzero;
    for (int ks = 0; ks < 2; ++ks) {
      bf16x8 ak[4];
      for (int nt = 0; nt < 4; ++nt)
        ak[nt] = *(const bf16x8*)&Ks[cur][(nt * 16 + l15) * 64 +
                                         ((ks * 4 + quad) ^ (l15 & 7)) * 8];
      for (int nt = 0; nt < 4; ++nt)
        st[nt] = __builtin_amdgcn_mfma_f32_16x16x32_bf16(ak[nt], aq[ks], st[nt], 0, 0, 0);
    }

    // p = exp2(s*SCL); pack 4 consecutive-k p's -> one ds_write_b64 per nt
    if (k0 + 63 <= q0 + myrow) {  // fully unmasked for whole wave
      for (int nt = 0; nt < 4; ++nt) {
        float p0 = __builtin_amdgcn_exp2f(st[nt][0] * SCL);
        float p1 = __builtin_amdgcn_exp2f(st[nt][1] * SCL);
        float p2 = __builtin_amdgcn_exp2f(st[nt][2] * SCL);
        float p3 = __builtin_amdgcn_exp2f(st[nt][3] * SCL);
        lsum += (p0 + p1) + (p2 + p3);
        uint2 pv; pv.x = pk2(p0, p1); pv.y = pk2(p2, p3);
        *(uint2*)&Ps[(myrow + l15) * 72 + nt * 16 + quad * 4] = pv;
      }
    } else {
      const int tq = q0 + myrow + l15;     // this lane's q column
      const int kbase = k0 + quad * 4;
      for (int nt = 0; nt < 4; ++nt) {
        float p[4];
        for (int r = 0; r < 4; ++r) {
          float pv = __builtin_amdgcn_exp2f(st[nt][r] * SCL);
          p[r] = (kbase + nt * 16 + r <= tq) ? pv : 0.f;
          lsum += p[r];
        }
        uint2 pv; pv.x = pk2(p[0], p[1]); pv.y = pk2(p[2], p[3]);
        *(uint2*)&Ps[(myrow + l15) * 72 + nt * 16 + quad * 4] = pv;
      }
    }

    // O += P V  (Ps rows are wave-private; in-wave LDS order suffices)
    for (int ks = 0; ks < 2; ++ks) {
      bf16x8 a = *(const bf16x8*)&Ps[(myrow + l15) * 72 + ks * 32 + quad * 8];
      bf16x8 bv[4];
      for (int nt = 0; nt < 4; ++nt)
        bv[nt] = *(const bf16x8*)&Vs[cur][(nt * 16 + l15) * 64 +
                                         ((ks * 4 + quad) ^ (l15 & 7)) * 8];
      for (int nt = 0; nt < 4; ++nt)
        O[nt] = __builtin_amdgcn_mfma_f32_16x16x32_bf16(a, bv[nt], O[nt], 0, 0, 0);
    }
  }

  // deferred l reduction: lanes with same l15 across 4 quads hold partials
  lsum += __shfl_xor(lsum, 16, 64);
  lsum += __shfl_xor(lsum, 32, 64);
  float inv[4];
  for (int r = 0; r < 4; ++r)
    inv[r] = 1.0f / __shfl(lsum, quad * 4 + r, 16);  // l for q-row quad*4+r

  // epilogue: normalize, stage via Ps (stride 72), coalesced 16 B stores
  for (int nt = 0; nt < 4; ++nt)
    for (int r = 0; r < 4; ++r)
      Ps[(myrow + quad * 4 + r) * 72 + nt * 16 + l15] = f2bf(O[nt][r] * inv[r]);
  __syncthreads();
  const int bb = bh >> 4, h = bh & 15;
  u16* dst = Og + ((size_t)bb * 2048 + q0) * 1024 + h * 64;
  int chunk = tid & 7, row0 = tid >> 3;
  for (int p = 0; p < 2; ++p) {
    int row = row0 + p * 64;
    u16x8 val = *(const u16x8*)&Ps[row * 72 + chunk * 8];
    *(u16x8*)(dst + (size_t)row * 1024 + chunk * 8) = val;
  }
}

// --------------------- output projection GEMM ---------------------
__global__ __launch_bounds__(256) void k_proj(
    const u16* __restrict__ Ag,      // [4096][1024] bf16
    const u16* __restrict__ Wt,      // [1024][1024] bf16 (W_proj^T)
    const float* __restrict__ bias,  // [1024]
    float* __restrict__ out) {       // [4096][1024] f32
  __shared__ alignas(16) u16 As[128 * 32];
  __shared__ alignas(16) u16 Bs[128 * 32];
  const int tid = threadIdx.x;
  const int lane = tid & 63, w = tid >> 6;
  const int quad = lane >> 4, l15 = lane & 15;
  const int m0 = blockIdx.y * 128, n0 = blockIdx.x * 128;
  const int lr = lane >> 2, lc = (lane & 3) * 8;
  const int wm = (w & 1) * 64, wn = (w >> 1) * 64;
  const f32x4 vzero = {0.f, 0.f, 0.f, 0.f};

  f32x4 acc[4][4];
  for (int i = 0; i < 4; ++i)
    for (int j = 0; j < 4; ++j) acc[i][j] = vzero;

  for (int kt = 0; kt < 1024; kt += 32) {
    __syncthreads();
    for (int i = 0; i < 2; ++i) {
      int row = w * 32 + i * 16;
      gld16(Ag + (size_t)(m0 + row + lr) * 1024 + kt + lc, &As[row * 32]);
      gld16(Wt + (size_t)(n0 + row + lr) * 1024 + kt + lc, &Bs[row * 32]);
    }
    __syncthreads();
    bf16x8 a[4], b[4];
    for (int mt = 0; mt < 4; ++mt)
      a[mt] = *(const bf16x8*)&As[(wm + mt * 16 + l15) * 32 + quad * 8];
    for (int nt = 0; nt < 4; ++nt)
      b[nt] = *(const bf16x8*)&Bs[(wn + nt * 16 + l15) * 32 + quad * 8];
    for (int mt = 0; mt < 4; ++mt)
      for (int nt = 0; nt < 4; ++nt)
        acc[mt][nt] = __builtin_amdgcn_mfma_f32_16x16x32_bf16(
            a[mt], b[nt], acc[mt][nt], 0, 0, 0);
  }

  for (int nt = 0; nt < 4; ++nt) {
    int n = n0 + wn + nt * 16 + l15;
    float bv = bias[n];
    for (int mt = 0; mt < 4; ++mt)
      for (int r = 0; r < 4; ++r) {
        int m = m0 + wm + mt * 16 + quad * 4 + r;
        out[(size_t)m * 1024 + n] = acc[mt][nt][r] + bv;
      }
  }
}

extern "C" void kernel_launch(void* const* d_in, const int* in_sizes, int n_in,
                              void* d_out, int out_size, void* d_ws, size_t ws_size,
                              hipStream_t stream) {
  (void)in_sizes; (void)n_in; (void)out_size; (void)ws_size;
  const float* x     = (const float*)d_in[0];
  const float* Wqkv  = (const float*)d_in[1];
  const float* bqkv  = (const float*)d_in[2];
  const float* Wproj = (const float*)d_in[3];
  const float* bproj = (const float*)d_in[4];
  float* out = (float*)d_out;

  char* ws = (char*)d_ws;
  size_t off = 0;
  u16* Xb    = (u16*)(ws + off); off += (size_t)4096 * 1024 * 2;   // x bf16
  u16* Wqkvt = (u16*)(ws + off); off += (size_t)3072 * 1024 * 2;   // W_qkv^T bf16
  u16* Wpt   = (u16*)(ws + off); off += (size_t)1024 * 1024 * 2;   // W_proj^T bf16
  u16* Qg    = (u16*)(ws + off); off += (size_t)2 * 16 * 2048 * 64 * 2;
  u16* Kg    = (u16*)(ws + off); off += (size_t)2 * 16 * 2048 * 64 * 2;
  u16* Vt    = (u16*)(ws + off); off += (size_t)2 * 16 * 64 * 2048 * 2;
  u16* Att   = (u16*)(ws + off); off += (size_t)4096 * 1024 * 2;
  float2* rope = (float2*)(ws + off); off += (size_t)2048 * 32 * sizeof(float2);

  k_prep<<<8448, 256, 0, stream>>>(x, Xb, Wqkv, Wqkvt, Wproj, Wpt, rope);
  k_qkv<<<dim3(24, 32), 256, 0, stream>>>(Xb, Wqkvt, bqkv, rope, Qg, Kg, Vt);
  k_attn<<<dim3(16, 32), 512, 0, stream>>>(Qg, Kg, Vt, Att);
  k_proj<<<dim3(8, 32), 256, 0, stream>>>(Att, Wpt, bproj, out);
}

// Round 5
// 196.387 us; speedup vs baseline: 2.6461x; 1.0010x over previous
//
#include <hip/hip_runtime.h>

// Problem constants: B=2, T=2048, C=1024, H=16, HS=64
typedef unsigned short u16;
typedef unsigned int u32;
typedef __bf16 bf16x8 __attribute__((ext_vector_type(8)));
typedef float f32x4 __attribute__((ext_vector_type(4)));
typedef u16 u16x4 __attribute__((ext_vector_type(4)));
typedef u16 u16x8 __attribute__((ext_vector_type(8)));

__device__ __forceinline__ u16 f2bf(float f) {
  u32 u = __builtin_bit_cast(u32, f);
  u += 0x7fffu + ((u >> 16) & 1u);   // round-to-nearest-even
  return (u16)(u >> 16);
}

// pack two f32 -> two bf16 (round-half-up) in one u32; a in low half.
__device__ __forceinline__ u32 pk2(float a, float b) {
  u32 ua = __builtin_bit_cast(u32, a) + 0x8000u;
  u32 ub = __builtin_bit_cast(u32, b) + 0x8000u;
  return __builtin_amdgcn_perm(ub, ua, 0x07060302);  // {ub.hi16, ua.hi16}
}

__device__ __forceinline__ void gld16(const void* g, void* l) {
  __builtin_amdgcn_global_load_lds(
      (const __attribute__((address_space(1))) void*)g,
      (__attribute__((address_space(3))) void*)l, 16, 0, 0);
}

// ---------------- merged prep kernel (one launch) ----------------
__global__ __launch_bounds__(256) void k_prep(
    const float* __restrict__ x, u16* __restrict__ xb,
    const float* __restrict__ Wqkv, u16* __restrict__ Wqkvt,
    const float* __restrict__ Wproj, u16* __restrict__ Wpt,
    float2* __restrict__ rope) {
  __shared__ float tile[32][33];
  const int tid = threadIdx.x;
  int bx = blockIdx.x;
  if (bx < 4096) {
    int i = (bx * 256 + tid) * 4;
    float4 v = *(const float4*)(x + i);
    u16x4 o = { f2bf(v.x), f2bf(v.y), f2bf(v.z), f2bf(v.w) };
    *(u16x4*)(xb + i) = o;
    return;
  }
  bx -= 4096;
  const float* src; u16* dst; int R, Cc, bxx, byy;
  if (bx < 3072) {
    src = Wqkv; dst = Wqkvt; R = 1024; Cc = 3072; bxx = bx % 96; byy = bx / 96;
  } else if (bx < 4096) {
    int b = bx - 3072;
    src = Wproj; dst = Wpt; R = 1024; Cc = 1024; bxx = b % 32; byy = b / 32;
  } else {
    int i = (bx - 4096) * 256 + tid;  // 0..65535
    int t = i >> 5, d = i & 31;
    float theta = expf(-(float)d * 0.28782313662425575f);  // ln(10000)/32
    float ang = (float)t * theta;
    rope[i] = make_float2(cosf(ang), sinf(ang));
    return;
  }
  int xx = tid & 31, yy = tid >> 5;
  int c0 = bxx * 32, r0 = byy * 32;
  for (int i = 0; i < 4; ++i)
    tile[yy + 8 * i][xx] = src[(size_t)(r0 + yy + 8 * i) * Cc + c0 + xx];
  __syncthreads();
  for (int i = 0; i < 4; ++i)
    dst[(size_t)(c0 + yy + 8 * i) * R + r0 + xx] = f2bf(tile[xx][yy + 8 * i]);
}

// --------------- QKV GEMM + bias + RoPE + scatter ---------------
// Per-wave operand order chosen by output region:
//  Q/K waves: mfma(W_frag, X_frag) -> lane = m(token), quad*4+r = 4 consecutive
//             hs -> RoPE pairs in-lane, packed b64 staging writes.
//  V waves:   mfma(X_frag, W_frag) -> lane = hs, quad*4+r = 4 consecutive m
//             -> packed b64 writes into transposed [hs][m] staging.
__global__ __launch_bounds__(256) void k_qkv(
    const u16* __restrict__ Xb,      // [4096][1024] bf16
    const u16* __restrict__ Wt,      // [3072][1024] bf16 (W_qkv^T)
    const float* __restrict__ bias,  // [3072]
    const float2* __restrict__ rope, // [2048][32]
    u16* __restrict__ Qg,            // [B,H,T,HS]
    u16* __restrict__ Kg,            // [B,H,T,HS]
    u16* __restrict__ Vt) {          // [B,H,HS,T]
  __shared__ alignas(16) u16 As[128 * 32];
  __shared__ alignas(16) u16 Bs[128 * 32];
  __shared__ alignas(16) u16 Es[2][9216];  // epilogue staging, one per n-halftile
  const int tid = threadIdx.x;
  const int lane = tid & 63, w = tid >> 6;
  const int quad = lane >> 4, l15 = lane & 15;
  const int m0 = blockIdx.y * 128, n0 = blockIdx.x * 128;
  const int lr = lane >> 2, lc = (lane & 3) * 8;
  const int wm = (w & 1) * 64, wn = (w >> 1) * 64;
  const f32x4 vzero = {0.f, 0.f, 0.f, 0.f};

  const int half = w >> 1;
  const int nh = n0 + half * 64;             // 64-aligned -> single region
  const int region = (nh % 192) >> 6;        // 0=Q 1=K 2=V
  const bool swapped = (region < 2);         // wave-uniform

  f32x4 acc[4][4];  // swapped: [nt][mt]; normal: [mt][nt]
  for (int i = 0; i < 4; ++i)
    for (int j = 0; j < 4; ++j) acc[i][j] = vzero;

  for (int kt = 0; kt < 1024; kt += 32) {
    __syncthreads();
    for (int i = 0; i < 2; ++i) {
      int row = w * 32 + i * 16;
      gld16(Xb + (size_t)(m0 + row + lr) * 1024 + kt + lc, &As[row * 32]);
      gld16(Wt + (size_t)(n0 + row + lr) * 1024 + kt + lc, &Bs[row * 32]);
    }
    __syncthreads();
    bf16x8 a[4], b[4];
    for (int mt = 0; mt < 4; ++mt)
      a[mt] = *(const bf16x8*)&As[(wm + mt * 16 + l15) * 32 + quad * 8];
    for (int nt = 0; nt < 4; ++nt)
      b[nt] = *(const bf16x8*)&Bs[(wn + nt * 16 + l15) * 32 + quad * 8];
    if (swapped) {
      for (int nt = 0; nt < 4; ++nt)
        for (int mt = 0; mt < 4; ++mt)
          acc[nt][mt] = __builtin_amdgcn_mfma_f32_16x16x32_bf16(
              b[nt], a[mt], acc[nt][mt], 0, 0, 0);
    } else {
      for (int mt = 0; mt < 4; ++mt)
        for (int nt = 0; nt < 4; ++nt)
          acc[mt][nt] = __builtin_amdgcn_mfma_f32_16x16x32_bf16(
              a[mt], b[nt], acc[mt][nt], 0, 0, 0);
    }
  }

  // ---- stage into LDS (bias + RoPE applied)
  if (swapped) {
    // lane: m = wm + mt*16 + l15; n-quad base c0 = nt*16 + quad*4 (consecutive hs)
    for (int nt = 0; nt < 4; ++nt) {
      float4 bv4 = *(const float4*)&bias[nh + nt * 16 + quad * 4];
      for (int mt = 0; mt < 4; ++mt) {
        int m_l = wm + mt * 16 + l15;
        int t = (m0 + m_l) & 2047;
        float4 cs = *(const float4*)&rope[t * 32 + nt * 8 + quad * 2];
        float v0 = acc[nt][mt][0] + bv4.x;
        float v1 = acc[nt][mt][1] + bv4.y;
        float v2 = acc[nt][mt][2] + bv4.z;
        float v3 = acc[nt][mt][3] + bv4.w;
        float r0 = fmaf(-v1, cs.y, v0 * cs.x);
        float r1 = fmaf( v0, cs.y, v1 * cs.x);
        float r2 = fmaf(-v3, cs.w, v2 * cs.z);
        float r3 = fmaf( v2, cs.w, v3 * cs.z);
        uint2 pv; pv.x = pk2(r0, r1); pv.y = pk2(r2, r3);
        *(uint2*)&Es[half][m_l * 72 + nt * 16 + quad * 4] = pv;
      }
    }
  } else {
    for (int nt = 0; nt < 4; ++nt) {
      int c = nt * 16 + l15;
      float bv = bias[nh + c];
      for (int mt = 0; mt < 4; ++mt) {
        float v0 = acc[mt][nt][0] + bv, v1 = acc[mt][nt][1] + bv;
        float v2 = acc[mt][nt][2] + bv, v3 = acc[mt][nt][3] + bv;
        uint2 pv; pv.x = pk2(v0, v1); pv.y = pk2(v2, v3);
        // transposed [c][m], r-values are consecutive m -> one b64 write
        *(uint2*)&Es[half][c * 136 + wm + mt * 16 + quad * 4] = pv;
      }
    }
  }
  __syncthreads();

  // ---- coalesced write-out: 16 B per lane
  const int bb = m0 >> 11, t0 = m0 & 2047;
  for (int hf = 0; hf < 2; ++hf) {
    const int nhf = n0 + hf * 64;
    const int hh = nhf / 192;
    const int reg = (nhf % 192) >> 6;
    if (reg < 2) {
      u16* dst = (reg == 0 ? Qg : Kg) +
                 ((size_t)(bb * 16 + hh) * 2048 + t0) * 64;
      int chunk = tid & 7, row0 = tid >> 3;
      for (int p = 0; p < 4; ++p) {
        int row = row0 + p * 32;
        u16x8 val = *(const u16x8*)&Es[hf][row * 72 + chunk * 8];
        *(u16x8*)(dst + (size_t)row * 64 + chunk * 8) = val;
      }
    } else {
      u16* dstv = Vt + (size_t)(bb * 16 + hh) * 64 * 2048 + t0;
      int mch = tid & 15, c0r = tid >> 4;
      for (int p = 0; p < 4; ++p) {
        int c = c0r + p * 16;
        u16x8 val = *(const u16x8*)&Es[hf][c * 136 + mch * 8];
        *(u16x8*)(dstv + (size_t)c * 2048 + mch * 8) = val;
      }
    }
  }
}

// ------------------- flash attention (causal) -------------------
// grid: (16, 32 bh), 512 threads = 8 waves. BQ=128, BKV=64, K/V double-buffered.
// Computes S^T = K·Q^T; packed b64 P-writes; no-max softmax; deferred l.
__global__ __launch_bounds__(512, 4) void k_attn(
    const u16* __restrict__ Qg, const u16* __restrict__ Kg,
    const u16* __restrict__ Vt, u16* __restrict__ Og) {  // Og: [4096][1024] bf16
  __shared__ alignas(16) u16 Ks[2][64 * 64];
  __shared__ alignas(16) u16 Vs[2][64 * 64];   // [hs][kk]
  __shared__ alignas(16) u16 Ps[128 * 72];
  const int tid = threadIdx.x, lane = tid & 63, w = tid >> 6;
  const int quad = lane >> 4, l15 = lane & 15;
  const int bh = blockIdx.y;
  // complementary-pairing hash: near-constant per-CU work
  int tmp = (blockIdx.x + bh) & 15;
  const int qt = (bh & 16) ? (15 - tmp) : tmp;
  const int q0 = qt * 128;
  const u16* Qh = Qg + (size_t)bh * 2048 * 64;
  const u16* Kh = Kg + (size_t)bh * 2048 * 64;
  const u16* Vh = Vt + (size_t)bh * 64 * 2048;
  const f32x4 vzero = {0.f, 0.f, 0.f, 0.f};
  const float SCL = 0.125f * 1.4426950408889634f;  // 1/sqrt(64) * log2(e)
  const int myrow = w * 16;

  // Q fragments direct to registers (row = q0 + myrow + l15)
  bf16x8 aq[2];
  {
    const u16* qp = Qh + (size_t)(q0 + myrow + l15) * 64 + quad * 8;
    aq[0] = *(const bf16x8*)(qp);
    aq[1] = *(const bf16x8*)(qp + 32);
  }

  // staging source swizzle: lane (r8,j) fetches global chunk j^r8 of its row
  const int r8 = lane >> 3, j8 = lane & 7;
  const int sw_c = (j8 ^ r8) * 8;

  float lsum = 0.f;
  f32x4 O[4];
  for (int nt = 0; nt < 4; ++nt) O[nt] = vzero;

  const int nk = 2 * qt + 2;
  // prologue: stage kb=0 into buffer 0
  gld16(Kh + (size_t)(w * 8 + r8) * 64 + sw_c, &Ks[0][w * 8 * 64]);
  gld16(Vh + (size_t)(w * 8 + r8) * 2048 + sw_c, &Vs[0][w * 8 * 64]);

  for (int kb = 0; kb < nk; ++kb) {
    const int k0 = kb * 64;
    const int cur = kb & 1;
    __syncthreads();  // buf[cur] staged+visible; buf[cur^1] readers (kb-1) done
    if (kb + 1 < nk) {
      const int k1 = k0 + 64;
      gld16(Kh + (size_t)(k1 + w * 8 + r8) * 64 + sw_c, &Ks[cur ^ 1][w * 8 * 64]);
      gld16(Vh + (size_t)(w * 8 + r8) * 2048 + k1 + sw_c, &Vs[cur ^ 1][w * 8 * 64]);
    }
    if (k0 > q0 + myrow + 15) continue;  // wave-uniform: fully masked

    // S^T = K Q^T : rows = k (64), cols = q (this wave's 16)
    f32x4 st[4];
    for (int nt = 0; nt < 4; ++nt) st[nt] = vzero;
    for (int ks = 0; ks < 2; ++ks) {
      bf16x8 ak[4];
      for (int nt = 0; nt < 4; ++nt)
        ak[nt] = *(const bf16x8*)&Ks[cur][(nt * 16 + l15) * 64 +
                                         ((ks * 4 + quad) ^ (l15 & 7)) * 8];
      for (int nt = 0; nt < 4; ++nt)
        st[nt] = __builtin_amdgcn_mfma_f32_16x16x32_bf16(ak[nt], aq[ks], st[nt], 0, 0, 0);
    }

    // p = exp2(s*SCL); pack 4 consecutive-k p's -> one ds_write_b64 per nt
    if (k0 + 63 <= q0 + myrow) {  // fully unmasked for whole wave
      for (int nt = 0; nt < 4; ++nt) {
        float p0 = __builtin_amdgcn_exp2f(st[nt][0] * SCL);
        float p1 = __builtin_amdgcn_exp2f(st[nt][1] * SCL);
        float p2 = __builtin_amdgcn_exp2f(st[nt][2] * SCL);
        float p3 = __builtin_amdgcn_exp2f(st[nt][3] * SCL);
        lsum += (p0 + p1) + (p2 + p3);
        uint2 pv; pv.x = pk2(p0, p1); pv.y = pk2(p2, p3);
        *(uint2*)&Ps[(myrow + l15) * 72 + nt * 16 + quad * 4] = pv;
      }
    } else {
      const int tq = q0 + myrow + l15;     // this lane's q column
      const int kbase = k0 + quad * 4;
      for (int nt = 0; nt < 4; ++nt) {
        float p[4];
        for (int r = 0; r < 4; ++r) {
          float pv = __builtin_amdgcn_exp2f(st[nt][r] * SCL);
          p[r] = (kbase + nt * 16 + r <= tq) ? pv : 0.f;
          lsum += p[r];
        }
        uint2 pv; pv.x = pk2(p[0], p[1]); pv.y = pk2(p[2], p[3]);
        *(uint2*)&Ps[(myrow + l15) * 72 + nt * 16 + quad * 4] = pv;
      }
    }

    // O += P V  (Ps rows are wave-private; in-wave LDS order suffices)
    for (int ks = 0; ks < 2; ++ks) {
      bf16x8 a = *(const bf16x8*)&Ps[(myrow + l15) * 72 + ks * 32 + quad * 8];
      bf16x8 bv[4];
      for (int nt = 0; nt < 4; ++nt)
        bv[nt] = *(const bf16x8*)&Vs[cur][(nt * 16 + l15) * 64 +
                                         ((ks * 4 + quad) ^ (l15 & 7)) * 8];
      for (int nt = 0; nt < 4; ++nt)
        O[nt] = __builtin_amdgcn_mfma_f32_16x16x32_bf16(a, bv[nt], O[nt], 0, 0, 0);
    }
  }

  // deferred l reduction: lanes with same l15 across 4 quads hold partials
  lsum += __shfl_xor(lsum, 16, 64);
  lsum += __shfl_xor(lsum, 32, 64);
  float inv[4];
  for (int r = 0; r < 4; ++r)
    inv[r] = 1.0f / __shfl(lsum, quad * 4 + r, 16);  // l for q-row quad*4+r

  // epilogue: normalize, stage via Ps (stride 72), coalesced 16 B stores
  for (int nt = 0; nt < 4; ++nt)
    for (int r = 0; r < 4; ++r)
      Ps[(myrow + quad * 4 + r) * 72 + nt * 16 + l15] = f2bf(O[nt][r] * inv[r]);
  __syncthreads();
  const int bb = bh >> 4, h = bh & 15;
  u16* dst = Og + ((size_t)bb * 2048 + q0) * 1024 + h * 64;
  int chunk = tid & 7, row0 = tid >> 3;
  for (int p = 0; p < 2; ++p) {
    int row = row0 + p * 64;
    u16x8 val = *(const u16x8*)&Ps[row * 72 + chunk * 8];
    *(u16x8*)(dst + (size_t)row * 1024 + chunk * 8) = val;
  }
}

// --------------------- output projection GEMM ---------------------
__global__ __launch_bounds__(256) void k_proj(
    const u16* __restrict__ Ag,      // [4096][1024] bf16
    const u16* __restrict__ Wt,      // [1024][1024] bf16 (W_proj^T)
    const float* __restrict__ bias,  // [1024]
    float* __restrict__ out) {       // [4096][1024] f32
  __shared__ alignas(16) u16 As[128 * 32];
  __shared__ alignas(16) u16 Bs[128 * 32];
  const int tid = threadIdx.x;
  const int lane = tid & 63, w = tid >> 6;
  const int quad = lane >> 4, l15 = lane & 15;
  const int m0 = blockIdx.y * 128, n0 = blockIdx.x * 128;
  const int lr = lane >> 2, lc = (lane & 3) * 8;
  const int wm = (w & 1) * 64, wn = (w >> 1) * 64;
  const f32x4 vzero = {0.f, 0.f, 0.f, 0.f};

  f32x4 acc[4][4];
  for (int i = 0; i < 4; ++i)
    for (int j = 0; j < 4; ++j) acc[i][j] = vzero;

  for (int kt = 0; kt < 1024; kt += 32) {
    __syncthreads();
    for (int i = 0; i < 2; ++i) {
      int row = w * 32 + i * 16;
      gld16(Ag + (size_t)(m0 + row + lr) * 1024 + kt + lc, &As[row * 32]);
      gld16(Wt + (size_t)(n0 + row + lr) * 1024 + kt + lc, &Bs[row * 32]);
    }
    __syncthreads();
    bf16x8 a[4], b[4];
    for (int mt = 0; mt < 4; ++mt)
      a[mt] = *(const bf16x8*)&As[(wm + mt * 16 + l15) * 32 + quad * 8];
    for (int nt = 0; nt < 4; ++nt)
      b[nt] = *(const bf16x8*)&Bs[(wn + nt * 16 + l15) * 32 + quad * 8];
    for (int mt = 0; mt < 4; ++mt)
      for (int nt = 0; nt < 4; ++nt)
        acc[mt][nt] = __builtin_amdgcn_mfma_f32_16x16x32_bf16(
            a[mt], b[nt], acc[mt][nt], 0, 0, 0);
  }

  for (int nt = 0; nt < 4; ++nt) {
    int n = n0 + wn + nt * 16 + l15;
    float bv = bias[n];
    for (int mt = 0; mt < 4; ++mt)
      for (int r = 0; r < 4; ++r) {
        int m = m0 + wm + mt * 16 + quad * 4 + r;
        out[(size_t)m * 1024 + n] = acc[mt][nt][r] + bv;
      }
  }
}

extern "C" void kernel_launch(void* const* d_in, const int* in_sizes, int n_in,
                              void* d_out, int out_size, void* d_ws, size_t ws_size,
                              hipStream_t stream) {
  (void)in_sizes; (void)n_in; (void)out_size; (void)ws_size;
  const float* x     = (const float*)d_in[0];
  const float* Wqkv  = (const float*)d_in[1];
  const float* bqkv  = (const float*)d_in[2];
  const float* Wproj = (const float*)d_in[3];
  const float* bproj = (const float*)d_in[4];
  float* out = (float*)d_out;

  char* ws = (char*)d_ws;
  size_t off = 0;
  u16* Xb    = (u16*)(ws + off); off += (size_t)4096 * 1024 * 2;   // x bf16
  u16* Wqkvt = (u16*)(ws + off); off += (size_t)3072 * 1024 * 2;   // W_qkv^T bf16
  u16* Wpt   = (u16*)(ws + off); off += (size_t)1024 * 1024 * 2;   // W_proj^T bf16
  u16* Qg    = (u16*)(ws + off); off += (size_t)2 * 16 * 2048 * 64 * 2;
  u16* Kg    = (u16*)(ws + off); off += (size_t)2 * 16 * 2048 * 64 * 2;
  u16* Vt    = (u16*)(ws + off); off += (size_t)2 * 16 * 64 * 2048 * 2;
  u16* Att   = (u16*)(ws + off); off += (size_t)4096 * 1024 * 2;
  float2* rope = (float2*)(ws + off); off += (size_t)2048 * 32 * sizeof(float2);

  k_prep<<<8448, 256, 0, stream>>>(x, Xb, Wqkv, Wqkvt, Wproj, Wpt, rope);
  k_qkv<<<dim3(24, 32), 256, 0, stream>>>(Xb, Wqkvt, bqkv, rope, Qg, Kg, Vt);
  k_attn<<<dim3(16, 32), 512, 0, stream>>>(Qg, Kg, Vt, Att);
  k_proj<<<dim3(8, 32), 256, 0, stream>>>(Att, Wpt, bproj, out);
}

// Round 6
// 174.620 us; speedup vs baseline: 2.9759x; 1.1247x over previous
//
#include <hip/hip_runtime.h>

// Problem constants: B=2, T=2048, C=1024, H=16, HS=64
typedef unsigned short u16;
typedef unsigned int u32;
typedef __bf16 bf16x8 __attribute__((ext_vector_type(8)));
typedef float f32x4 __attribute__((ext_vector_type(4)));
typedef u16 u16x4 __attribute__((ext_vector_type(4)));
typedef u16 u16x8 __attribute__((ext_vector_type(8)));

__device__ __forceinline__ u16 f2bf(float f) {
  u32 u = __builtin_bit_cast(u32, f);
  u += 0x7fffu + ((u >> 16) & 1u);   // round-to-nearest-even
  return (u16)(u >> 16);
}

// pack two f32 -> two bf16 (round-half-up) in one u32; a in low half.
__device__ __forceinline__ u32 pk2(float a, float b) {
  u32 ua = __builtin_bit_cast(u32, a) + 0x8000u;
  u32 ub = __builtin_bit_cast(u32, b) + 0x8000u;
  return __builtin_amdgcn_perm(ub, ua, 0x07060302);  // {ub.hi16, ua.hi16}
}

__device__ __forceinline__ void gld16(const void* g, void* l) {
  __builtin_amdgcn_global_load_lds(
      (const __attribute__((address_space(1))) void*)g,
      (__attribute__((address_space(3))) void*)l, 16, 0, 0);
}

// ---------------- merged prep kernel (one launch) ----------------
__global__ __launch_bounds__(256) void k_prep(
    const float* __restrict__ x, u16* __restrict__ xb,
    const float* __restrict__ Wqkv, u16* __restrict__ Wqkvt,
    const float* __restrict__ Wproj, u16* __restrict__ Wpt,
    float2* __restrict__ rope) {
  __shared__ float tile[32][33];
  const int tid = threadIdx.x;
  int bx = blockIdx.x;
  if (bx < 4096) {
    int i = (bx * 256 + tid) * 4;
    float4 v = *(const float4*)(x + i);
    u16x4 o = { f2bf(v.x), f2bf(v.y), f2bf(v.z), f2bf(v.w) };
    *(u16x4*)(xb + i) = o;
    return;
  }
  bx -= 4096;
  const float* src; u16* dst; int R, Cc, bxx, byy;
  if (bx < 3072) {
    src = Wqkv; dst = Wqkvt; R = 1024; Cc = 3072; bxx = bx % 96; byy = bx / 96;
  } else if (bx < 4096) {
    int b = bx - 3072;
    src = Wproj; dst = Wpt; R = 1024; Cc = 1024; bxx = b % 32; byy = b / 32;
  } else {
    int i = (bx - 4096) * 256 + tid;  // 0..65535
    int t = i >> 5, d = i & 31;
    float theta = expf(-(float)d * 0.28782313662425575f);  // ln(10000)/32
    float ang = (float)t * theta;
    rope[i] = make_float2(cosf(ang), sinf(ang));
    return;
  }
  int xx = tid & 31, yy = tid >> 5;
  int c0 = bxx * 32, r0 = byy * 32;
  for (int i = 0; i < 4; ++i)
    tile[yy + 8 * i][xx] = src[(size_t)(r0 + yy + 8 * i) * Cc + c0 + xx];
  __syncthreads();
  for (int i = 0; i < 4; ++i)
    dst[(size_t)(c0 + yy + 8 * i) * R + r0 + xx] = f2bf(tile[xx][yy + 8 * i]);
}

// --------------- QKV GEMM + bias + RoPE + scatter ---------------
// BK=64, XOR-chunk-swizzled As/Bs (conflict-free b128 reads), epilogue staging
// UNIONED with As/Bs -> 36 KB LDS -> 4 blocks/CU. Uniform swapped MFMA order
// mfma(W_frag, X_frag): lane = m(token), quad*4+r = 4 consecutive hs ->
// Q/K: in-lane RoPE + packed b64 staging; V: scalar b16 into transposed [c][m].
__global__ __launch_bounds__(256, 4) void k_qkv(
    const u16* __restrict__ Xb,      // [4096][1024] bf16
    const u16* __restrict__ Wt,      // [3072][1024] bf16 (W_qkv^T)
    const float* __restrict__ bias,  // [3072]
    const float2* __restrict__ rope, // [2048][32]
    u16* __restrict__ Qg,            // [B,H,T,HS]
    u16* __restrict__ Kg,            // [B,H,T,HS]
    u16* __restrict__ Vt) {          // [B,H,HS,T]
  __shared__ alignas(16) u16 smem[18432];  // 36 KB: As|Bs in K-loop, Es after
  u16* As = smem;           // [128][64]
  u16* Bs = smem + 8192;    // [128][64]
  const int tid = threadIdx.x;
  const int lane = tid & 63, w = tid >> 6;
  const int quad = lane >> 4, l15 = lane & 15;
  const int m0 = blockIdx.y * 128, n0 = blockIdx.x * 128;
  const int wm = (w & 1) * 64, wn = (w >> 1) * 64;
  const int srow = lane >> 3, sj = lane & 7;
  const int sw = (sj ^ srow) * 8;   // swizzled source u16 offset
  const f32x4 vzero = {0.f, 0.f, 0.f, 0.f};

  f32x4 acc[4][4];  // [nt][mt] (swapped order)
  for (int i = 0; i < 4; ++i)
    for (int j = 0; j < 4; ++j) acc[i][j] = vzero;

  for (int kt = 0; kt < 1024; kt += 64) {
    __syncthreads();
    for (int i = 0; i < 4; ++i) {
      int row = w * 32 + i * 8;
      gld16(Xb + (size_t)(m0 + row + srow) * 1024 + kt + sw, &As[row * 64]);
      gld16(Wt + (size_t)(n0 + row + srow) * 1024 + kt + sw, &Bs[row * 64]);
    }
    __syncthreads();
    for (int ks = 0; ks < 2; ++ks) {
      const int cc = ((ks * 4 + quad) ^ (l15 & 7)) * 8;
      bf16x8 a[4], b[4];
      for (int mt = 0; mt < 4; ++mt)
        a[mt] = *(const bf16x8*)&As[(wm + mt * 16 + l15) * 64 + cc];
      for (int nt = 0; nt < 4; ++nt)
        b[nt] = *(const bf16x8*)&Bs[(wn + nt * 16 + l15) * 64 + cc];
      for (int nt = 0; nt < 4; ++nt)
        for (int mt = 0; mt < 4; ++mt)
          acc[nt][mt] = __builtin_amdgcn_mfma_f32_16x16x32_bf16(
              b[nt], a[mt], acc[nt][mt], 0, 0, 0);
    }
  }
  __syncthreads();  // all waves done reading As/Bs; safe to overwrite with Es

  // ---- stage into LDS (bias + RoPE applied), wave-uniform region per half
  const int half = w >> 1;
  const int nh = n0 + half * 64;             // 64-aligned -> single region
  const int region = (nh % 192) >> 6;        // 0=Q 1=K 2=V
  u16* Eh = smem + half * 9216;
  if (region < 2) {
    // lane: m = wm + mt*16 + l15; quad*4+r = 4 consecutive hs
    for (int nt = 0; nt < 4; ++nt) {
      float4 bv4 = *(const float4*)&bias[nh + nt * 16 + quad * 4];
      for (int mt = 0; mt < 4; ++mt) {
        int m_l = wm + mt * 16 + l15;
        int t = (m0 + m_l) & 2047;
        float4 cs = *(const float4*)&rope[t * 32 + nt * 8 + quad * 2];
        float v0 = acc[nt][mt][0] + bv4.x;
        float v1 = acc[nt][mt][1] + bv4.y;
        float v2 = acc[nt][mt][2] + bv4.z;
        float v3 = acc[nt][mt][3] + bv4.w;
        float r0 = fmaf(-v1, cs.y, v0 * cs.x);
        float r1 = fmaf( v0, cs.y, v1 * cs.x);
        float r2 = fmaf(-v3, cs.w, v2 * cs.z);
        float r3 = fmaf( v2, cs.w, v3 * cs.z);
        uint2 pv; pv.x = pk2(r0, r1); pv.y = pk2(r2, r3);
        *(uint2*)&Eh[m_l * 72 + nt * 16 + quad * 4] = pv;
      }
    }
  } else {
    // V: transposed [c][m] stride 136; c = nt*16+quad*4+r varies with r
    for (int nt = 0; nt < 4; ++nt) {
      float4 bv4 = *(const float4*)&bias[nh + nt * 16 + quad * 4];
      for (int mt = 0; mt < 4; ++mt) {
        int m_l = wm + mt * 16 + l15;
        int cb = nt * 16 + quad * 4;
        Eh[(cb + 0) * 136 + m_l] = f2bf(acc[nt][mt][0] + bv4.x);
        Eh[(cb + 1) * 136 + m_l] = f2bf(acc[nt][mt][1] + bv4.y);
        Eh[(cb + 2) * 136 + m_l] = f2bf(acc[nt][mt][2] + bv4.z);
        Eh[(cb + 3) * 136 + m_l] = f2bf(acc[nt][mt][3] + bv4.w);
      }
    }
  }
  __syncthreads();

  // ---- coalesced write-out: 16 B per lane
  const int bb = m0 >> 11, t0 = m0 & 2047;
  for (int hf = 0; hf < 2; ++hf) {
    const int nhf = n0 + hf * 64;
    const int hh = nhf / 192;
    const int reg = (nhf % 192) >> 6;
    const u16* Ef = smem + hf * 9216;
    if (reg < 2) {
      u16* dst = (reg == 0 ? Qg : Kg) +
                 ((size_t)(bb * 16 + hh) * 2048 + t0) * 64;
      int chunk = tid & 7, row0 = tid >> 3;
      for (int p = 0; p < 4; ++p) {
        int row = row0 + p * 32;
        u16x8 val = *(const u16x8*)&Ef[row * 72 + chunk * 8];
        *(u16x8*)(dst + (size_t)row * 64 + chunk * 8) = val;
      }
    } else {
      u16* dstv = Vt + (size_t)(bb * 16 + hh) * 64 * 2048 + t0;
      int mch = tid & 15, c0r = tid >> 4;
      for (int p = 0; p < 4; ++p) {
        int c = c0r + p * 16;
        u16x8 val = *(const u16x8*)&Ef[c * 136 + mch * 8];
        *(u16x8*)(dstv + (size_t)c * 2048 + mch * 8) = val;
      }
    }
  }
}

// ------------------- flash attention (causal) -------------------
// grid: (16, 32 bh), 512 threads = 8 waves. BQ=128, BKV=64, K/V double-buffered.
// Computes S^T = K·Q^T; packed b64 P-writes; no-max softmax; deferred l.
__global__ __launch_bounds__(512, 4) void k_attn(
    const u16* __restrict__ Qg, const u16* __restrict__ Kg,
    const u16* __restrict__ Vt, u16* __restrict__ Og) {  // Og: [4096][1024] bf16
  __shared__ alignas(16) u16 Ks[2][64 * 64];
  __shared__ alignas(16) u16 Vs[2][64 * 64];   // [hs][kk]
  __shared__ alignas(16) u16 Ps[128 * 72];
  const int tid = threadIdx.x, lane = tid & 63, w = tid >> 6;
  const int quad = lane >> 4, l15 = lane & 15;
  const int bh = blockIdx.y;
  // complementary-pairing hash: near-constant per-CU work
  int tmp = (blockIdx.x + bh) & 15;
  const int qt = (bh & 16) ? (15 - tmp) : tmp;
  const int q0 = qt * 128;
  const u16* Qh = Qg + (size_t)bh * 2048 * 64;
  const u16* Kh = Kg + (size_t)bh * 2048 * 64;
  const u16* Vh = Vt + (size_t)bh * 64 * 2048;
  const f32x4 vzero = {0.f, 0.f, 0.f, 0.f};
  const float SCL = 0.125f * 1.4426950408889634f;  // 1/sqrt(64) * log2(e)
  const int myrow = w * 16;

  // Q fragments direct to registers (row = q0 + myrow + l15)
  bf16x8 aq[2];
  {
    const u16* qp = Qh + (size_t)(q0 + myrow + l15) * 64 + quad * 8;
    aq[0] = *(const bf16x8*)(qp);
    aq[1] = *(const bf16x8*)(qp + 32);
  }

  // staging source swizzle: lane (r8,j) fetches global chunk j^r8 of its row
  const int r8 = lane >> 3, j8 = lane & 7;
  const int sw_c = (j8 ^ r8) * 8;

  float lsum = 0.f;
  f32x4 O[4];
  for (int nt = 0; nt < 4; ++nt) O[nt] = vzero;

  const int nk = 2 * qt + 2;
  // prologue: stage kb=0 into buffer 0
  gld16(Kh + (size_t)(w * 8 + r8) * 64 + sw_c, &Ks[0][w * 8 * 64]);
  gld16(Vh + (size_t)(w * 8 + r8) * 2048 + sw_c, &Vs[0][w * 8 * 64]);

  for (int kb = 0; kb < nk; ++kb) {
    const int k0 = kb * 64;
    const int cur = kb & 1;
    __syncthreads();  // buf[cur] staged+visible; buf[cur^1] readers (kb-1) done
    if (kb + 1 < nk) {
      const int k1 = k0 + 64;
      gld16(Kh + (size_t)(k1 + w * 8 + r8) * 64 + sw_c, &Ks[cur ^ 1][w * 8 * 64]);
      gld16(Vh + (size_t)(w * 8 + r8) * 2048 + k1 + sw_c, &Vs[cur ^ 1][w * 8 * 64]);
    }
    if (k0 > q0 + myrow + 15) continue;  // wave-uniform: fully masked

    // S^T = K Q^T : rows = k (64), cols = q (this wave's 16)
    f32x4 st[4];
    for (int nt = 0; nt < 4; ++nt) st[nt] = vzero;
    for (int ks = 0; ks < 2; ++ks) {
      bf16x8 ak[4];
      for (int nt = 0; nt < 4; ++nt)
        ak[nt] = *(const bf16x8*)&Ks[cur][(nt * 16 + l15) * 64 +
                                         ((ks * 4 + quad) ^ (l15 & 7)) * 8];
      for (int nt = 0; nt < 4; ++nt)
        st[nt] = __builtin_amdgcn_mfma_f32_16x16x32_bf16(ak[nt], aq[ks], st[nt], 0, 0, 0);
    }

    // p = exp2(s*SCL); pack 4 consecutive-k p's -> one ds_write_b64 per nt
    if (k0 + 63 <= q0 + myrow) {  // fully unmasked for whole wave
      for (int nt = 0; nt < 4; ++nt) {
        float p0 = __builtin_amdgcn_exp2f(st[nt][0] * SCL);
        float p1 = __builtin_amdgcn_exp2f(st[nt][1] * SCL);
        float p2 = __builtin_amdgcn_exp2f(st[nt][2] * SCL);
        float p3 = __builtin_amdgcn_exp2f(st[nt][3] * SCL);
        lsum += (p0 + p1) + (p2 + p3);
        uint2 pv; pv.x = pk2(p0, p1); pv.y = pk2(p2, p3);
        *(uint2*)&Ps[(myrow + l15) * 72 + nt * 16 + quad * 4] = pv;
      }
    } else {
      const int tq = q0 + myrow + l15;     // this lane's q column
      const int kbase = k0 + quad * 4;
      for (int nt = 0; nt < 4; ++nt) {
        float p[4];
        for (int r = 0; r < 4; ++r) {
          float pv = __builtin_amdgcn_exp2f(st[nt][r] * SCL);
          p[r] = (kbase + nt * 16 + r <= tq) ? pv : 0.f;
          lsum += p[r];
        }
        uint2 pv; pv.x = pk2(p[0], p[1]); pv.y = pk2(p[2], p[3]);
        *(uint2*)&Ps[(myrow + l15) * 72 + nt * 16 + quad * 4] = pv;
      }
    }

    // O += P V  (Ps rows are wave-private; in-wave LDS order suffices)
    for (int ks = 0; ks < 2; ++ks) {
      bf16x8 a = *(const bf16x8*)&Ps[(myrow + l15) * 72 + ks * 32 + quad * 8];
      bf16x8 bv[4];
      for (int nt = 0; nt < 4; ++nt)
        bv[nt] = *(const bf16x8*)&Vs[cur][(nt * 16 + l15) * 64 +
                                         ((ks * 4 + quad) ^ (l15 & 7)) * 8];
      for (int nt = 0; nt < 4; ++nt)
        O[nt] = __builtin_amdgcn_mfma_f32_16x16x32_bf16(a, bv[nt], O[nt], 0, 0, 0);
    }
  }

  // deferred l reduction: lanes with same l15 across 4 quads hold partials
  lsum += __shfl_xor(lsum, 16, 64);
  lsum += __shfl_xor(lsum, 32, 64);
  float inv[4];
  for (int r = 0; r < 4; ++r)
    inv[r] = 1.0f / __shfl(lsum, quad * 4 + r, 16);  // l for q-row quad*4+r

  // epilogue: normalize, stage via Ps (stride 72), coalesced 16 B stores
  for (int nt = 0; nt < 4; ++nt)
    for (int r = 0; r < 4; ++r)
      Ps[(myrow + quad * 4 + r) * 72 + nt * 16 + l15] = f2bf(O[nt][r] * inv[r]);
  __syncthreads();
  const int bb = bh >> 4, h = bh & 15;
  u16* dst = Og + ((size_t)bb * 2048 + q0) * 1024 + h * 64;
  int chunk = tid & 7, row0 = tid >> 3;
  for (int p = 0; p < 2; ++p) {
    int row = row0 + p * 64;
    u16x8 val = *(const u16x8*)&Ps[row * 72 + chunk * 8];
    *(u16x8*)(dst + (size_t)row * 1024 + chunk * 8) = val;
  }
}

// --------------------- output projection GEMM ---------------------
// BM=64, BN=128, BK=64, swizzled staging. grid (8, 64) = 512 blocks (2/CU).
__global__ __launch_bounds__(256, 4) void k_proj(
    const u16* __restrict__ Ag,      // [4096][1024] bf16
    const u16* __restrict__ Wt,      // [1024][1024] bf16 (W_proj^T)
    const float* __restrict__ bias,  // [1024]
    float* __restrict__ out) {       // [4096][1024] f32
  __shared__ alignas(16) u16 As[64 * 64];
  __shared__ alignas(16) u16 Bs[128 * 64];
  const int tid = threadIdx.x;
  const int lane = tid & 63, w = tid >> 6;
  const int quad = lane >> 4, l15 = lane & 15;
  const int m0 = blockIdx.y * 64, n0 = blockIdx.x * 128;
  const int wm = (w & 1) * 32, wn = (w >> 1) * 64;
  const int srow = lane >> 3, sj = lane & 7;
  const int sw = (sj ^ srow) * 8;
  const f32x4 vzero = {0.f, 0.f, 0.f, 0.f};

  f32x4 acc[2][4];
  for (int i = 0; i < 2; ++i)
    for (int j = 0; j < 4; ++j) acc[i][j] = vzero;

  for (int kt = 0; kt < 1024; kt += 64) {
    __syncthreads();
    for (int i = 0; i < 2; ++i) {
      int row = w * 16 + i * 8;
      gld16(Ag + (size_t)(m0 + row + srow) * 1024 + kt + sw, &As[row * 64]);
    }
    for (int i = 0; i < 4; ++i) {
      int row = w * 32 + i * 8;
      gld16(Wt + (size_t)(n0 + row + srow) * 1024 + kt + sw, &Bs[row * 64]);
    }
    __syncthreads();
    for (int ks = 0; ks < 2; ++ks) {
      const int cc = ((ks * 4 + quad) ^ (l15 & 7)) * 8;
      bf16x8 a[2], b[4];
      for (int mt = 0; mt < 2; ++mt)
        a[mt] = *(const bf16x8*)&As[(wm + mt * 16 + l15) * 64 + cc];
      for (int nt = 0; nt < 4; ++nt)
        b[nt] = *(const bf16x8*)&Bs[(wn + nt * 16 + l15) * 64 + cc];
      for (int mt = 0; mt < 2; ++mt)
        for (int nt = 0; nt < 4; ++nt)
          acc[mt][nt] = __builtin_amdgcn_mfma_f32_16x16x32_bf16(
              a[mt], b[nt], acc[mt][nt], 0, 0, 0);
    }
  }

  for (int nt = 0; nt < 4; ++nt) {
    int n = n0 + wn + nt * 16 + l15;
    float bv = bias[n];
    for (int mt = 0; mt < 2; ++mt)
      for (int r = 0; r < 4; ++r) {
        int m = m0 + wm + mt * 16 + quad * 4 + r;
        out[(size_t)m * 1024 + n] = acc[mt][nt][r] + bv;
      }
  }
}

extern "C" void kernel_launch(void* const* d_in, const int* in_sizes, int n_in,
                              void* d_out, int out_size, void* d_ws, size_t ws_size,
                              hipStream_t stream) {
  (void)in_sizes; (void)n_in; (void)out_size; (void)ws_size;
  const float* x     = (const float*)d_in[0];
  const float* Wqkv  = (const float*)d_in[1];
  const float* bqkv  = (const float*)d_in[2];
  const float* Wproj = (const float*)d_in[3];
  const float* bproj = (const float*)d_in[4];
  float* out = (float*)d_out;

  char* ws = (char*)d_ws;
  size_t off = 0;
  u16* Xb    = (u16*)(ws + off); off += (size_t)4096 * 1024 * 2;   // x bf16
  u16* Wqkvt = (u16*)(ws + off); off += (size_t)3072 * 1024 * 2;   // W_qkv^T bf16
  u16* Wpt   = (u16*)(ws + off); off += (size_t)1024 * 1024 * 2;   // W_proj^T bf16
  u16* Qg    = (u16*)(ws + off); off += (size_t)2 * 16 * 2048 * 64 * 2;
  u16* Kg    = (u16*)(ws + off); off += (size_t)2 * 16 * 2048 * 64 * 2;
  u16* Vt    = (u16*)(ws + off); off += (size_t)2 * 16 * 64 * 2048 * 2;
  u16* Att   = (u16*)(ws + off); off += (size_t)4096 * 1024 * 2;
  float2* rope = (float2*)(ws + off); off += (size_t)2048 * 32 * sizeof(float2);

  k_prep<<<8448, 256, 0, stream>>>(x, Xb, Wqkv, Wqkvt, Wproj, Wpt, rope);
  k_qkv<<<dim3(24, 32), 256, 0, stream>>>(Xb, Wqkvt, bqkv, rope, Qg, Kg, Vt);
  k_attn<<<dim3(16, 32), 512, 0, stream>>>(Qg, Kg, Vt, Att);
  k_proj<<<dim3(8, 64), 256, 0, stream>>>(Att, Wpt, bproj, out);
}